// Round 2
// baseline (1961.271 us; speedup 1.0000x reference)
//
#include <hip/hip_runtime.h>
#include <math.h>

#define TPB 256

// ---------------------------------------------------------------------------
// Geometry:
//   x: [8, 1, 128, 1024] f32
//   L0: CI=1,  CO=16, 128x1024, pool -> 64x512   (fused offsets)
//   L1: CI=16, CO=32, 64x512,   pool -> 32x256   (fused offsets)
//   L2: CI=32, CO=48, 32x256,   pool -> 16x128   (off kernel + og-split 2)
//   L3: CI=48, CO=64, 16x128,   no pool          (off kernel + og-split 4)
//   L4: CI=64, CO=80, 16x128,   no pool -> d_out (off kernel + og-split 4)
// ---------------------------------------------------------------------------

__global__ void zero_stats_kernel(double* st, int n) {
  int i = blockIdx.x * blockDim.x + threadIdx.x;
  if (i < n) st[i] = 0.0;
}

// ---------------------------------------------------------------------------
// Fused deform conv: one thread per output pixel. Offsets computed in-thread
// (direct 3x3 conv), bilinear gathers straight from global, weights broadcast
// from LDS as float4 (1 ds_read_b128 per 16 FMA, conflict-free broadcast).
// ---------------------------------------------------------------------------
template<int CI, int CO>
__global__ __launch_bounds__(TPB, 4) void dfc_fused(
    const float* __restrict__ x, const float* __restrict__ woff,
    const float* __restrict__ boff, const float* __restrict__ wmain,
    float* __restrict__ out, int B, int H, int W) {
  __shared__ float s_wm[CI * 9 * CO];   // [c*9+k][o]
  __shared__ float s_wo[CI * 9 * 20];   // [c*9+t][j] padded to 20

  const int tid = threadIdx.x;
  for (int t = tid; t < CI * 9 * CO; t += TPB) {
    int ck = t / CO, o = t % CO;
    s_wm[t] = wmain[(size_t)o * CI * 9 + ck];
  }
  for (int t = tid; t < CI * 9 * 18; t += TPB) {
    int ck = t / 18, j = t % 18;
    s_wo[ck * 20 + j] = woff[(size_t)j * CI * 9 + ck];
  }
  __syncthreads();

  const int idx = blockIdx.x * TPB + tid;
  const int HW = H * W;
  const int w = idx % W;
  const int h = (idx / W) % H;
  const int b = idx / HW;
  const float* xb = x + (size_t)b * CI * HW;

  // ---- offset conv (18 channels) in registers
  float offv[20];
#pragma unroll
  for (int j = 0; j < 18; j++) offv[j] = boff[j];
#pragma unroll 2
  for (int c = 0; c < CI; c++) {
    const float* xc = xb + (size_t)c * HW;
#pragma unroll
    for (int t = 0; t < 9; t++) {
      int yy = h - 1 + t / 3, xx = w - 1 + t % 3;
      float v = 0.f;
      if (yy >= 0 && yy < H && xx >= 0 && xx < W) v = xc[yy * W + xx];
      const float* wr = &s_wo[(c * 9 + t) * 20];
#pragma unroll
      for (int j4 = 0; j4 < 16; j4 += 4) {
        float4 wv = *(const float4*)&wr[j4];
        offv[j4 + 0] = fmaf(v, wv.x, offv[j4 + 0]);
        offv[j4 + 1] = fmaf(v, wv.y, offv[j4 + 1]);
        offv[j4 + 2] = fmaf(v, wv.z, offv[j4 + 2]);
        offv[j4 + 3] = fmaf(v, wv.w, offv[j4 + 3]);
      }
      offv[16] = fmaf(v, wr[16], offv[16]);
      offv[17] = fmaf(v, wr[17], offv[17]);
    }
  }

  // ---- main deformable conv
  float acc[CO];
#pragma unroll
  for (int o = 0; o < CO; o++) acc[o] = 0.f;

#pragma unroll
  for (int k = 0; k < 9; k++) {
    float py = (float)(h - 1 + k / 3) + offv[2 * k];
    float px = (float)(w - 1 + k % 3) + offv[2 * k + 1];
    float fy = floorf(py), fx = floorf(px);
    float wy = py - fy, wx = px - fx;
    int y0 = (int)fy, x0 = (int)fx;
    int y1 = y0 + 1, x1 = x0 + 1;
    bool vy0 = (y0 >= 0) & (y0 < H), vy1 = (y1 >= 0) & (y1 < H);
    bool vx0 = (x0 >= 0) & (x0 < W), vx1 = (x1 >= 0) & (x1 < W);
    int yc0 = min(max(y0, 0), H - 1), yc1 = min(max(y1, 0), H - 1);
    int xc0 = min(max(x0, 0), W - 1), xc1 = min(max(x1, 0), W - 1);
    float w00 = (vy0 && vx0) ? (1.f - wy) * (1.f - wx) : 0.f;
    float w01 = (vy0 && vx1) ? (1.f - wy) * wx : 0.f;
    float w10 = (vy1 && vx0) ? wy * (1.f - wx) : 0.f;
    float w11 = (vy1 && vx1) ? wy * wx : 0.f;
    int a00 = yc0 * W + xc0, a01 = yc0 * W + xc1;
    int a10 = yc1 * W + xc0, a11 = yc1 * W + xc1;
#pragma unroll 2
    for (int c = 0; c < CI; c++) {
      const float* xc = xb + (size_t)c * HW;
      float sv = xc[a00] * w00 + xc[a01] * w01 + xc[a10] * w10 + xc[a11] * w11;
      const float* wr = &s_wm[(c * 9 + k) * CO];
#pragma unroll
      for (int o4 = 0; o4 < CO; o4 += 4) {
        float4 wv = *(const float4*)&wr[o4];
        acc[o4 + 0] = fmaf(sv, wv.x, acc[o4 + 0]);
        acc[o4 + 1] = fmaf(sv, wv.y, acc[o4 + 1]);
        acc[o4 + 2] = fmaf(sv, wv.z, acc[o4 + 2]);
        acc[o4 + 3] = fmaf(sv, wv.w, acc[o4 + 3]);
      }
    }
  }

  float* op = out + (size_t)b * CO * HW + h * W + w;
#pragma unroll
  for (int o = 0; o < CO; o++) op[(size_t)o * HW] = acc[o];
}

// ---------------------------------------------------------------------------
// Parallel offset conv: thread = (pixel, offset-channel j). j is wave-uniform
// (H*W multiple of 256) so woff reads are uniform/broadcast.
// ---------------------------------------------------------------------------
template<int CI>
__global__ __launch_bounds__(TPB, 4) void off_conv_pj(
    const float* __restrict__ x, const float* __restrict__ woff,
    const float* __restrict__ boff, float* __restrict__ off,
    int B, int H, int W) {
  const int idx = blockIdx.x * TPB + threadIdx.x;
  const int HW = H * W;
  const int w = idx % W;
  const int h = (idx / W) % H;
  const int j = (idx / HW) % 18;
  const int b = idx / (18 * HW);
  const float* xb = x + (size_t)b * CI * HW;
  const float* wj = woff + (size_t)j * CI * 9;
  float acc = boff[j];
#pragma unroll 2
  for (int c = 0; c < CI; c++) {
    const float* xc = xb + (size_t)c * HW;
#pragma unroll
    for (int t = 0; t < 9; t++) {
      int yy = h - 1 + t / 3, xx = w - 1 + t % 3;
      float v = 0.f;
      if (yy >= 0 && yy < H && xx >= 0 && xx < W) v = xc[yy * W + xx];
      acc = fmaf(v, wj[c * 9 + t], acc);
    }
  }
  off[idx] = acc;
}

// ---------------------------------------------------------------------------
// Deform conv with output-channel split: block handles 256 pixels for one
// og group of COG=CO/OGC channels; offsets read from off buffer.
// ---------------------------------------------------------------------------
template<int CI, int CO, int OGC>
__global__ __launch_bounds__(TPB, 1) void dfc_og(
    const float* __restrict__ x, const float* __restrict__ off,
    const float* __restrict__ wmain, float* __restrict__ out,
    int B, int H, int W) {
  constexpr int COG = CO / OGC;
  __shared__ float s_wm[CI * 9 * COG];

  const int og = blockIdx.x % OGC;
  const int pxb = blockIdx.x / OGC;
  const int tid = threadIdx.x;
  for (int t = tid; t < CI * 9 * COG; t += TPB) {
    int ck = t / COG, o = t % COG;
    s_wm[t] = wmain[((size_t)(og * COG + o) * CI * 9) + ck];
  }
  __syncthreads();

  const int idx = pxb * TPB + tid;
  const int HW = H * W;
  const int w = idx % W;
  const int h = (idx / W) % H;
  const int b = idx / HW;
  const float* xb = x + (size_t)b * CI * HW;

  float offv[18];
  const float* ob = off + (size_t)b * 18 * HW + h * W + w;
#pragma unroll
  for (int j = 0; j < 18; j++) offv[j] = ob[(size_t)j * HW];

  float acc[COG];
#pragma unroll
  for (int o = 0; o < COG; o++) acc[o] = 0.f;

#pragma unroll
  for (int k = 0; k < 9; k++) {
    float py = (float)(h - 1 + k / 3) + offv[2 * k];
    float px = (float)(w - 1 + k % 3) + offv[2 * k + 1];
    float fy = floorf(py), fx = floorf(px);
    float wy = py - fy, wx = px - fx;
    int y0 = (int)fy, x0 = (int)fx;
    int y1 = y0 + 1, x1 = x0 + 1;
    bool vy0 = (y0 >= 0) & (y0 < H), vy1 = (y1 >= 0) & (y1 < H);
    bool vx0 = (x0 >= 0) & (x0 < W), vx1 = (x1 >= 0) & (x1 < W);
    int yc0 = min(max(y0, 0), H - 1), yc1 = min(max(y1, 0), H - 1);
    int xc0 = min(max(x0, 0), W - 1), xc1 = min(max(x1, 0), W - 1);
    float w00 = (vy0 && vx0) ? (1.f - wy) * (1.f - wx) : 0.f;
    float w01 = (vy0 && vx1) ? (1.f - wy) * wx : 0.f;
    float w10 = (vy1 && vx0) ? wy * (1.f - wx) : 0.f;
    float w11 = (vy1 && vx1) ? wy * wx : 0.f;
    int a00 = yc0 * W + xc0, a01 = yc0 * W + xc1;
    int a10 = yc1 * W + xc0, a11 = yc1 * W + xc1;
#pragma unroll 2
    for (int c = 0; c < CI; c++) {
      const float* xc = xb + (size_t)c * HW;
      float sv = xc[a00] * w00 + xc[a01] * w01 + xc[a10] * w10 + xc[a11] * w11;
      const float* wr = &s_wm[(c * 9 + k) * COG];
#pragma unroll
      for (int o4 = 0; o4 < COG; o4 += 4) {
        float4 wv = *(const float4*)&wr[o4];
        acc[o4 + 0] = fmaf(sv, wv.x, acc[o4 + 0]);
        acc[o4 + 1] = fmaf(sv, wv.y, acc[o4 + 1]);
        acc[o4 + 2] = fmaf(sv, wv.z, acc[o4 + 2]);
        acc[o4 + 3] = fmaf(sv, wv.w, acc[o4 + 3]);
      }
    }
  }

  float* op = out + ((size_t)b * CO + og * COG) * HW + h * W + w;
#pragma unroll
  for (int o = 0; o < COG; o++) op[(size_t)o * HW] = acc[o];
}

// ---------------------------------------------------------------------------
// BatchNorm (training stats) + LeakyReLU (+ optional 2x2 maxpool)
// ---------------------------------------------------------------------------
__global__ void bn_stats_kernel(const float* __restrict__ y,
                                double* __restrict__ st,
                                int B, int C, int HW, int NB) {
  int c = blockIdx.x / NB;
  int sl = blockIdx.x % NB;
  int tid = threadIdx.x;
  double s = 0.0, s2 = 0.0;
  for (int b = 0; b < B; b++) {
    const float* p = y + ((size_t)b * C + c) * HW;
    for (int i = sl * TPB + tid; i < HW; i += NB * TPB) {
      float v = p[i];
      s += v;
      s2 += (double)v * (double)v;
    }
  }
  __shared__ double rs[TPB], rq[TPB];
  rs[tid] = s;
  rq[tid] = s2;
  __syncthreads();
  for (int o = TPB / 2; o > 0; o >>= 1) {
    if (tid < o) { rs[tid] += rs[tid + o]; rq[tid] += rq[tid + o]; }
    __syncthreads();
  }
  if (tid == 0) {
    atomicAdd(&st[2 * c], rs[0]);
    atomicAdd(&st[2 * c + 1], rq[0]);
  }
}

__global__ void bn_finalize_kernel(const double* __restrict__ st,
                                   const float* __restrict__ g,
                                   const float* __restrict__ bb,
                                   float* __restrict__ ss, int C, int N) {
  int c = threadIdx.x;
  if (c >= C) return;
  double mean = st[2 * c] / N;
  double var = st[2 * c + 1] / N - mean * mean;
  float inv = (float)(1.0 / sqrt(var + 1e-5));
  float sc = g[c] * inv;
  ss[c] = sc;
  ss[C + c] = bb[c] - (float)mean * sc;
}

__global__ void bn_apply_kernel(const float* __restrict__ y,
                                const float* __restrict__ ss,
                                float* __restrict__ out, int C, int HW, int n) {
  int i = blockIdx.x * TPB + threadIdx.x;
  if (i >= n) return;
  int c = (i / HW) % C;
  float v = fmaf(y[i], ss[c], ss[C + c]);
  out[i] = v > 0.f ? v : 0.01f * v;
}

__global__ void bn_apply_pool_kernel(const float* __restrict__ y,
                                     const float* __restrict__ ss,
                                     float* __restrict__ out,
                                     int C, int H, int W, int n) {
  int i = blockIdx.x * TPB + threadIdx.x;
  if (i >= n) return;
  int Wp = W >> 1, Hp = H >> 1;
  int pw = i % Wp;
  int ph = (i / Wp) % Hp;
  int c = (i / (Wp * Hp)) % C;
  int b = i / (Wp * Hp * C);
  const float* yp = y + (((size_t)b * C + c) * H + 2 * ph) * W + 2 * pw;
  float sc = ss[c], sh = ss[C + c];
  float v0 = fmaf(yp[0], sc, sh);     v0 = v0 > 0.f ? v0 : 0.01f * v0;
  float v1 = fmaf(yp[1], sc, sh);     v1 = v1 > 0.f ? v1 : 0.01f * v1;
  float v2 = fmaf(yp[W], sc, sh);     v2 = v2 > 0.f ? v2 : 0.01f * v2;
  float v3 = fmaf(yp[W + 1], sc, sh); v3 = v3 > 0.f ? v3 : 0.01f * v3;
  out[i] = fmaxf(fmaxf(v0, v1), fmaxf(v2, v3));
}

extern "C" void kernel_launch(void* const* d_in, const int* in_sizes, int n_in,
                              void* d_out, int out_size, void* d_ws, size_t ws_size,
                              hipStream_t stream) {
  const float* x = (const float*)d_in[0];
  const float *woff[5], *boff[5], *wm[5], *g[5], *bb[5];
  for (int i = 0; i < 5; i++) {
    woff[i] = (const float*)d_in[1 + 5 * i + 0];
    boff[i] = (const float*)d_in[1 + 5 * i + 1];
    wm[i]   = (const float*)d_in[1 + 5 * i + 2];
    g[i]    = (const float*)d_in[1 + 5 * i + 3];
    bb[i]   = (const float*)d_in[1 + 5 * i + 4];
  }

  const size_t need = (size_t)(16777216 + 4718592 + 4194304 + 2097152) * 4 + 1280 + 640;
  if (ws_size < need) return;

  float* conv_buf = (float*)d_ws;          // up to [8,16,128,1024] = 67 MB
  float* off_buf = conv_buf + 16777216;    // offsets for L2..L4
  float* xa = off_buf + 4718592;           // x1 / x3
  float* xb2 = xa + 4194304;               // x2 / x4
  double* st = (double*)(xb2 + 2097152);
  float* ss = (float*)(st + 160);

  const int B = 8;

  auto bn = [&](const float* ybuf, int C, int H, int W, int NB,
                const float* gg, const float* bbb, float* outp, bool pool) {
    zero_stats_kernel<<<1, TPB, 0, stream>>>(st, 2 * C);
    bn_stats_kernel<<<C * NB, TPB, 0, stream>>>(ybuf, st, B, C, H * W, NB);
    bn_finalize_kernel<<<1, TPB, 0, stream>>>(st, gg, bbb, ss, C, B * H * W);
    if (pool) {
      int n = B * C * (H / 2) * (W / 2);
      bn_apply_pool_kernel<<<(n + TPB - 1) / TPB, TPB, 0, stream>>>(ybuf, ss, outp, C, H, W, n);
    } else {
      int n = B * C * H * W;
      bn_apply_kernel<<<(n + TPB - 1) / TPB, TPB, 0, stream>>>(ybuf, ss, outp, C, H * W, n);
    }
  };

  // ---- Layer 0: CI=1, CO=16, 128x1024, fused offsets, pool -> xa
  {
    const int H = 128, W = 1024;
    dfc_fused<1, 16><<<B * H * W / TPB, TPB, 0, stream>>>(
        x, woff[0], boff[0], wm[0], conv_buf, B, H, W);
    bn(conv_buf, 16, H, W, 32, g[0], bb[0], xa, true);
  }
  // ---- Layer 1: CI=16, CO=32, 64x512, fused offsets, pool -> xb2
  {
    const int H = 64, W = 512;
    dfc_fused<16, 32><<<B * H * W / TPB, TPB, 0, stream>>>(
        xa, woff[1], boff[1], wm[1], conv_buf, B, H, W);
    bn(conv_buf, 32, H, W, 32, g[1], bb[1], xb2, true);
  }
  // ---- Layer 2: CI=32, CO=48, 32x256, off kernel + og-split 2, pool -> xa
  {
    const int H = 32, W = 256;
    off_conv_pj<32><<<B * 18 * H * W / TPB, TPB, 0, stream>>>(
        xb2, woff[2], boff[2], off_buf, B, H, W);
    dfc_og<32, 48, 2><<<(B * H * W / TPB) * 2, TPB, 0, stream>>>(
        xb2, off_buf, wm[2], conv_buf, B, H, W);
    bn(conv_buf, 48, H, W, 16, g[2], bb[2], xa, true);
  }
  // ---- Layer 3: CI=48, CO=64, 16x128, off kernel + og-split 4 -> xb2
  {
    const int H = 16, W = 128;
    off_conv_pj<48><<<B * 18 * H * W / TPB, TPB, 0, stream>>>(
        xa, woff[3], boff[3], off_buf, B, H, W);
    dfc_og<48, 64, 4><<<(B * H * W / TPB) * 4, TPB, 0, stream>>>(
        xa, off_buf, wm[3], conv_buf, B, H, W);
    bn(conv_buf, 64, H, W, 8, g[3], bb[3], xb2, false);
  }
  // ---- Layer 4: CI=64, CO=80, 16x128, off kernel + og-split 4 -> d_out
  {
    const int H = 16, W = 128;
    off_conv_pj<64><<<B * 18 * H * W / TPB, TPB, 0, stream>>>(
        xb2, woff[4], boff[4], off_buf, B, H, W);
    dfc_og<64, 80, 4><<<(B * H * W / TPB) * 4, TPB, 0, stream>>>(
        xb2, off_buf, wm[4], conv_buf, B, H, W);
    bn(conv_buf, 80, H, W, 8, g[4], bb[4], (float*)d_out, false);
  }
}

// Round 3
// 1754.475 us; speedup vs baseline: 1.1179x; 1.1179x over previous
//
#include <hip/hip_runtime.h>
#include <math.h>

#define TPB 256

// ---------------------------------------------------------------------------
// Geometry:
//   x: [8, 1, 128, 1024] f32
//   L0: CI=1,  CO=16, 128x1024, pool -> 64x512   (fused offsets, acc16)
//   L1: CI=16, CO=32, 64x512,   pool -> 32x256   (off_j6 + og-split 2, COG=16)
//   L2: CI=32, CO=48, 32x256,   pool -> 16x128   (off_j6 + og-split 3, COG=16)
//   L3: CI=48, CO=64, 16x128,   no pool          (off_j6 + og-split 4, COG=16)
//   L4: CI=64, CO=80, 16x128,   no pool -> d_out (off_j6 + og-split 5, COG=16)
// Register discipline: max 16 accumulators + 18 offsets per thread, all
// statically indexed (spill avoidance — R2's L1 kernel spilled acc[32] and
// ran at 4% VALUBusy with 3.4 GB of scratch traffic).
// ---------------------------------------------------------------------------

// ---------------------------------------------------------------------------
// L0 only: fused offset conv (CI=1) + deform conv, one thread per pixel,
// all 16 output channels in registers.
// ---------------------------------------------------------------------------
template<int CI, int CO>
__global__ __launch_bounds__(TPB, 4) void dfc_fused(
    const float* __restrict__ x, const float* __restrict__ woff,
    const float* __restrict__ boff, const float* __restrict__ wmain,
    float* __restrict__ out, int B, int H, int W) {
  __shared__ float s_wm[CI * 9 * CO];   // [c*9+k][o]
  __shared__ float s_wo[CI * 9 * 20];   // [c*9+t][j] padded to 20

  const int tid = threadIdx.x;
  for (int t = tid; t < CI * 9 * CO; t += TPB) {
    int ck = t / CO, o = t % CO;
    s_wm[t] = wmain[(size_t)o * CI * 9 + ck];
  }
  for (int t = tid; t < CI * 9 * 18; t += TPB) {
    int ck = t / 18, j = t % 18;
    s_wo[ck * 20 + j] = woff[(size_t)j * CI * 9 + ck];
  }
  __syncthreads();

  const int idx = blockIdx.x * TPB + tid;
  const int HW = H * W;
  const int w = idx % W;
  const int h = (idx / W) % H;
  const int b = idx / HW;
  const float* xb = x + (size_t)b * CI * HW;

  float offv[18];
#pragma unroll
  for (int j = 0; j < 18; j++) offv[j] = boff[j];
#pragma unroll
  for (int c = 0; c < CI; c++) {
    const float* xc = xb + (size_t)c * HW;
#pragma unroll
    for (int t = 0; t < 9; t++) {
      int yy = h - 1 + t / 3, xx = w - 1 + t % 3;
      float v = 0.f;
      if (yy >= 0 && yy < H && xx >= 0 && xx < W) v = xc[yy * W + xx];
      const float* wr = &s_wo[(c * 9 + t) * 20];
#pragma unroll
      for (int j = 0; j < 18; j++) offv[j] = fmaf(v, wr[j], offv[j]);
    }
  }

  float acc[CO];
#pragma unroll
  for (int o = 0; o < CO; o++) acc[o] = 0.f;

#pragma unroll
  for (int k = 0; k < 9; k++) {
    float py = (float)(h - 1 + k / 3) + offv[2 * k];
    float px = (float)(w - 1 + k % 3) + offv[2 * k + 1];
    float fy = floorf(py), fx = floorf(px);
    float wy = py - fy, wx = px - fx;
    int y0 = (int)fy, x0 = (int)fx;
    int y1 = y0 + 1, x1 = x0 + 1;
    bool vy0 = (y0 >= 0) & (y0 < H), vy1 = (y1 >= 0) & (y1 < H);
    bool vx0 = (x0 >= 0) & (x0 < W), vx1 = (x1 >= 0) & (x1 < W);
    int yc0 = min(max(y0, 0), H - 1), yc1 = min(max(y1, 0), H - 1);
    int xc0 = min(max(x0, 0), W - 1), xc1 = min(max(x1, 0), W - 1);
    float w00 = (vy0 && vx0) ? (1.f - wy) * (1.f - wx) : 0.f;
    float w01 = (vy0 && vx1) ? (1.f - wy) * wx : 0.f;
    float w10 = (vy1 && vx0) ? wy * (1.f - wx) : 0.f;
    float w11 = (vy1 && vx1) ? wy * wx : 0.f;
    int a00 = yc0 * W + xc0, a01 = yc0 * W + xc1;
    int a10 = yc1 * W + xc0, a11 = yc1 * W + xc1;
#pragma unroll
    for (int c = 0; c < CI; c++) {
      const float* xc = xb + (size_t)c * HW;
      float sv = xc[a00] * w00 + xc[a01] * w01 + xc[a10] * w10 + xc[a11] * w11;
      const float* wr = &s_wm[(c * 9 + k) * CO];
#pragma unroll
      for (int o4 = 0; o4 < CO; o4 += 4) {
        float4 wv = *(const float4*)&wr[o4];
        acc[o4 + 0] = fmaf(sv, wv.x, acc[o4 + 0]);
        acc[o4 + 1] = fmaf(sv, wv.y, acc[o4 + 1]);
        acc[o4 + 2] = fmaf(sv, wv.z, acc[o4 + 2]);
        acc[o4 + 3] = fmaf(sv, wv.w, acc[o4 + 3]);
      }
    }
  }

  float* op = out + (size_t)b * CO * HW + h * W + w;
#pragma unroll
  for (int o = 0; o < CO; o++) op[(size_t)o * HW] = acc[o];
}

// ---------------------------------------------------------------------------
// Offset conv: thread = (pixel, group of 6 offset channels). acc[6].
// Weight reads are wave-uniform (j-group/b uniform within a wave).
// ---------------------------------------------------------------------------
template<int CI>
__global__ __launch_bounds__(TPB, 4) void off_conv_j6(
    const float* __restrict__ x, const float* __restrict__ woff,
    const float* __restrict__ boff, float* __restrict__ off,
    int B, int H, int W) {
  const int idx = blockIdx.x * TPB + threadIdx.x;
  const int HW = H * W;
  const int px = idx % HW;
  const int jg = (idx / HW) % 3;
  const int b = idx / (3 * HW);
  const int w = px % W, h = px / W;
  const float* xb = x + (size_t)b * CI * HW;
  const float* wj = woff + (size_t)jg * 6 * CI * 9;  // [6][CI*9]
  float acc[6];
#pragma unroll
  for (int u = 0; u < 6; u++) acc[u] = boff[jg * 6 + u];
#pragma unroll 2
  for (int c = 0; c < CI; c++) {
    const float* xc = xb + (size_t)c * HW;
#pragma unroll
    for (int t = 0; t < 9; t++) {
      int yy = h - 1 + t / 3, xx = w - 1 + t % 3;
      float v = 0.f;
      if (yy >= 0 && yy < H && xx >= 0 && xx < W) v = xc[yy * W + xx];
#pragma unroll
      for (int u = 0; u < 6; u++)
        acc[u] = fmaf(v, wj[(size_t)u * CI * 9 + c * 9 + t], acc[u]);
    }
  }
#pragma unroll
  for (int u = 0; u < 6; u++)
    off[((size_t)b * 18 + jg * 6 + u) * HW + px] = acc[u];
}

// ---------------------------------------------------------------------------
// Deform conv, output-channel split: block = 256 pixels x one og group of
// COG=CO/OGC channels (COG=16 everywhere). acc[16].
// ---------------------------------------------------------------------------
template<int CI, int CO, int OGC>
__global__ __launch_bounds__(TPB, 4) void dfc_og(
    const float* __restrict__ x, const float* __restrict__ off,
    const float* __restrict__ wmain, float* __restrict__ out,
    int B, int H, int W) {
  constexpr int COG = CO / OGC;
  __shared__ float s_wm[CI * 9 * COG];

  const int og = blockIdx.x % OGC;
  const int pxb = blockIdx.x / OGC;
  const int tid = threadIdx.x;
  for (int t = tid; t < CI * 9 * COG; t += TPB) {
    int ck = t / COG, o = t % COG;
    s_wm[t] = wmain[((size_t)(og * COG + o) * CI * 9) + ck];
  }
  __syncthreads();

  const int idx = pxb * TPB + tid;
  const int HW = H * W;
  const int w = idx % W;
  const int h = (idx / W) % H;
  const int b = idx / HW;
  const float* xb = x + (size_t)b * CI * HW;

  float offv[18];
  const float* ob = off + (size_t)b * 18 * HW + h * W + w;
#pragma unroll
  for (int j = 0; j < 18; j++) offv[j] = ob[(size_t)j * HW];

  float acc[COG];
#pragma unroll
  for (int o = 0; o < COG; o++) acc[o] = 0.f;

#pragma unroll
  for (int k = 0; k < 9; k++) {
    float py = (float)(h - 1 + k / 3) + offv[2 * k];
    float px = (float)(w - 1 + k % 3) + offv[2 * k + 1];
    float fy = floorf(py), fx = floorf(px);
    float wy = py - fy, wx = px - fx;
    int y0 = (int)fy, x0 = (int)fx;
    int y1 = y0 + 1, x1 = x0 + 1;
    bool vy0 = (y0 >= 0) & (y0 < H), vy1 = (y1 >= 0) & (y1 < H);
    bool vx0 = (x0 >= 0) & (x0 < W), vx1 = (x1 >= 0) & (x1 < W);
    int yc0 = min(max(y0, 0), H - 1), yc1 = min(max(y1, 0), H - 1);
    int xc0 = min(max(x0, 0), W - 1), xc1 = min(max(x1, 0), W - 1);
    float w00 = (vy0 && vx0) ? (1.f - wy) * (1.f - wx) : 0.f;
    float w01 = (vy0 && vx1) ? (1.f - wy) * wx : 0.f;
    float w10 = (vy1 && vx0) ? wy * (1.f - wx) : 0.f;
    float w11 = (vy1 && vx1) ? wy * wx : 0.f;
    int a00 = yc0 * W + xc0, a01 = yc0 * W + xc1;
    int a10 = yc1 * W + xc0, a11 = yc1 * W + xc1;
#pragma unroll 2
    for (int c = 0; c < CI; c++) {
      const float* xc = xb + (size_t)c * HW;
      float sv = xc[a00] * w00 + xc[a01] * w01 + xc[a10] * w10 + xc[a11] * w11;
      const float* wr = &s_wm[(c * 9 + k) * COG];
#pragma unroll
      for (int o4 = 0; o4 < COG; o4 += 4) {
        float4 wv = *(const float4*)&wr[o4];
        acc[o4 + 0] = fmaf(sv, wv.x, acc[o4 + 0]);
        acc[o4 + 1] = fmaf(sv, wv.y, acc[o4 + 1]);
        acc[o4 + 2] = fmaf(sv, wv.z, acc[o4 + 2]);
        acc[o4 + 3] = fmaf(sv, wv.w, acc[o4 + 3]);
      }
    }
  }

  float* op = out + ((size_t)b * CO + og * COG) * HW + h * W + w;
#pragma unroll
  for (int o = 0; o < COG; o++) op[(size_t)o * HW] = acc[o];
}

// ---------------------------------------------------------------------------
// BatchNorm (training stats) + LeakyReLU (+ optional 2x2 maxpool)
// ---------------------------------------------------------------------------
__global__ void bn_stats_kernel(const float* __restrict__ y,
                                double* __restrict__ st,
                                int B, int C, int HW, int NB) {
  int c = blockIdx.x / NB;
  int sl = blockIdx.x % NB;
  int tid = threadIdx.x;
  double s = 0.0, s2 = 0.0;
  int HW4 = HW >> 2;
  for (int b = 0; b < B; b++) {
    const float4* p = (const float4*)(y + ((size_t)b * C + c) * HW);
    for (int i = sl * TPB + tid; i < HW4; i += NB * TPB) {
      float4 v = p[i];
      s += (double)v.x + (double)v.y + (double)v.z + (double)v.w;
      s2 += (double)v.x * v.x + (double)v.y * v.y
          + (double)v.z * v.z + (double)v.w * v.w;
    }
  }
  __shared__ double rs[TPB], rq[TPB];
  rs[tid] = s;
  rq[tid] = s2;
  __syncthreads();
  for (int o = TPB / 2; o > 0; o >>= 1) {
    if (tid < o) { rs[tid] += rs[tid + o]; rq[tid] += rq[tid + o]; }
    __syncthreads();
  }
  if (tid == 0) {
    atomicAdd(&st[2 * c], rs[0]);
    atomicAdd(&st[2 * c + 1], rq[0]);
  }
}

__global__ void bn_finalize_kernel(const double* __restrict__ st,
                                   const float* __restrict__ g,
                                   const float* __restrict__ bb,
                                   float* __restrict__ ss, int C, int N) {
  int c = threadIdx.x;
  if (c >= C) return;
  double mean = st[2 * c] / N;
  double var = st[2 * c + 1] / N - mean * mean;
  float inv = (float)(1.0 / sqrt(var + 1e-5));
  float sc = g[c] * inv;
  ss[c] = sc;
  ss[C + c] = bb[c] - (float)mean * sc;
}

__global__ void bn_apply_kernel(const float* __restrict__ y,
                                const float* __restrict__ ss,
                                float* __restrict__ out, int C, int HW, int n) {
  int i = blockIdx.x * TPB + threadIdx.x;
  if (i >= n) return;
  int c = (i / HW) % C;
  float v = fmaf(y[i], ss[c], ss[C + c]);
  out[i] = v > 0.f ? v : 0.01f * v;
}

__global__ void bn_apply_pool_kernel(const float* __restrict__ y,
                                     const float* __restrict__ ss,
                                     float* __restrict__ out,
                                     int C, int H, int W, int n) {
  int i = blockIdx.x * TPB + threadIdx.x;
  if (i >= n) return;
  int Wp = W >> 1, Hp = H >> 1;
  int pw = i % Wp;
  int ph = (i / Wp) % Hp;
  int c = (i / (Wp * Hp)) % C;
  int b = i / (Wp * Hp * C);
  const float* yp = y + (((size_t)b * C + c) * H + 2 * ph) * W + 2 * pw;
  float sc = ss[c], sh = ss[C + c];
  float2 t0 = *(const float2*)yp;
  float2 t1 = *(const float2*)(yp + W);
  float v0 = fmaf(t0.x, sc, sh); v0 = v0 > 0.f ? v0 : 0.01f * v0;
  float v1 = fmaf(t0.y, sc, sh); v1 = v1 > 0.f ? v1 : 0.01f * v1;
  float v2 = fmaf(t1.x, sc, sh); v2 = v2 > 0.f ? v2 : 0.01f * v2;
  float v3 = fmaf(t1.y, sc, sh); v3 = v3 > 0.f ? v3 : 0.01f * v3;
  out[i] = fmaxf(fmaxf(v0, v1), fmaxf(v2, v3));
}

extern "C" void kernel_launch(void* const* d_in, const int* in_sizes, int n_in,
                              void* d_out, int out_size, void* d_ws, size_t ws_size,
                              hipStream_t stream) {
  const float* x = (const float*)d_in[0];
  const float *woff[5], *boff[5], *wm[5], *g[5], *bb[5];
  for (int i = 0; i < 5; i++) {
    woff[i] = (const float*)d_in[1 + 5 * i + 0];
    boff[i] = (const float*)d_in[1 + 5 * i + 1];
    wm[i]   = (const float*)d_in[1 + 5 * i + 2];
    g[i]    = (const float*)d_in[1 + 5 * i + 3];
    bb[i]   = (const float*)d_in[1 + 5 * i + 4];
  }

  const size_t need = (size_t)(16777216 + 4718592 + 4194304 + 2097152) * 4 + 1280 + 640;
  if (ws_size < need) return;

  float* conv_buf = (float*)d_ws;          // up to [8,16,128,1024] = 67 MB
  float* off_buf = conv_buf + 16777216;    // offsets (max L1: 18.9 MB)
  float* xa = off_buf + 4718592;           // x1 / x3
  float* xb2 = xa + 4194304;               // x2 / x4
  double* st = (double*)(xb2 + 2097152);
  float* ss = (float*)(st + 160);

  const int B = 8;

  auto bn = [&](const float* ybuf, int C, int H, int W, int NB,
                const float* gg, const float* bbb, float* outp, bool pool) {
    hipMemsetAsync(st, 0, 2 * C * sizeof(double), stream);
    bn_stats_kernel<<<C * NB, TPB, 0, stream>>>(ybuf, st, B, C, H * W, NB);
    bn_finalize_kernel<<<1, TPB, 0, stream>>>(st, gg, bbb, ss, C, B * H * W);
    if (pool) {
      int n = B * C * (H / 2) * (W / 2);
      bn_apply_pool_kernel<<<(n + TPB - 1) / TPB, TPB, 0, stream>>>(ybuf, ss, outp, C, H, W, n);
    } else {
      int n = B * C * H * W;
      bn_apply_kernel<<<(n + TPB - 1) / TPB, TPB, 0, stream>>>(ybuf, ss, outp, C, H * W, n);
    }
  };

  // ---- Layer 0: CI=1, CO=16, 128x1024, fused offsets, pool -> xa
  {
    const int H = 128, W = 1024;
    dfc_fused<1, 16><<<B * H * W / TPB, TPB, 0, stream>>>(
        x, woff[0], boff[0], wm[0], conv_buf, B, H, W);
    bn(conv_buf, 16, H, W, 32, g[0], bb[0], xa, true);
  }
  // ---- Layer 1: CI=16, CO=32, 64x512, pool -> xb2
  {
    const int H = 64, W = 512;
    off_conv_j6<16><<<B * 3 * H * W / TPB, TPB, 0, stream>>>(
        xa, woff[1], boff[1], off_buf, B, H, W);
    dfc_og<16, 32, 2><<<(B * H * W / TPB) * 2, TPB, 0, stream>>>(
        xa, off_buf, wm[1], conv_buf, B, H, W);
    bn(conv_buf, 32, H, W, 32, g[1], bb[1], xb2, true);
  }
  // ---- Layer 2: CI=32, CO=48, 32x256, pool -> xa
  {
    const int H = 32, W = 256;
    off_conv_j6<32><<<B * 3 * H * W / TPB, TPB, 0, stream>>>(
        xb2, woff[2], boff[2], off_buf, B, H, W);
    dfc_og<32, 48, 3><<<(B * H * W / TPB) * 3, TPB, 0, stream>>>(
        xb2, off_buf, wm[2], conv_buf, B, H, W);
    bn(conv_buf, 48, H, W, 16, g[2], bb[2], xa, true);
  }
  // ---- Layer 3: CI=48, CO=64, 16x128, no pool -> xb2
  {
    const int H = 16, W = 128;
    off_conv_j6<48><<<B * 3 * H * W / TPB, TPB, 0, stream>>>(
        xa, woff[3], boff[3], off_buf, B, H, W);
    dfc_og<48, 64, 4><<<(B * H * W / TPB) * 4, TPB, 0, stream>>>(
        xa, off_buf, wm[3], conv_buf, B, H, W);
    bn(conv_buf, 64, H, W, 8, g[3], bb[3], xb2, false);
  }
  // ---- Layer 4: CI=64, CO=80, 16x128, no pool -> d_out
  {
    const int H = 16, W = 128;
    off_conv_j6<64><<<B * 3 * H * W / TPB, TPB, 0, stream>>>(
        xb2, woff[4], boff[4], off_buf, B, H, W);
    dfc_og<64, 80, 5><<<(B * H * W / TPB) * 5, TPB, 0, stream>>>(
        xb2, off_buf, wm[4], conv_buf, B, H, W);
    bn(conv_buf, 80, H, W, 8, g[4], bb[4], (float*)d_out, false);
  }
}

// Round 4
// 1551.059 us; speedup vs baseline: 1.2645x; 1.1311x over previous
//
#include <hip/hip_runtime.h>
#include <math.h>

#define TPB 256

// ---------------------------------------------------------------------------
// Geometry:
//   x: [8, 1, 128, 1024] f32
//   L0: CI=1,  CO=16, 128x1024, pool -> 64x512   (fused offsets, acc16)
//   L1: CI=16, CO=32, 64x512,   pool -> 32x256   (off_lds + og-split 2, COG=16)
//   L2: CI=32, CO=48, 32x256,   pool -> 16x128   (off_lds + og-split 3, COG=16)
//   L3: CI=48, CO=64, 16x128,   no pool          (off_lds + og-split 4, COG=16)
//   L4: CI=64, CO=80, 16x128,   no pool -> d_out (off_lds + og-split 5, COG=16)
// Register discipline: max 16 accumulators + 18 offsets per thread, all
// statically indexed; ALL per-MAC weight operands come from LDS broadcasts
// (R2: acc[32] spilled; R3: 108 in-flight global weight loads spilled the
// offset conv — 596 MB scratch writes, 4% VALUBusy).
// ---------------------------------------------------------------------------

// ---------------------------------------------------------------------------
// L0 only: fused offset conv (CI=1) + deform conv, one thread per pixel,
// all 16 output channels in registers.
// ---------------------------------------------------------------------------
template<int CI, int CO>
__global__ __launch_bounds__(TPB, 4) void dfc_fused(
    const float* __restrict__ x, const float* __restrict__ woff,
    const float* __restrict__ boff, const float* __restrict__ wmain,
    float* __restrict__ out, int B, int H, int W) {
  __shared__ float s_wm[CI * 9 * CO];   // [c*9+k][o]
  __shared__ float s_wo[CI * 9 * 20];   // [c*9+t][j] padded to 20

  const int tid = threadIdx.x;
  for (int t = tid; t < CI * 9 * CO; t += TPB) {
    int ck = t / CO, o = t % CO;
    s_wm[t] = wmain[(size_t)o * CI * 9 + ck];
  }
  for (int t = tid; t < CI * 9 * 18; t += TPB) {
    int ck = t / 18, j = t % 18;
    s_wo[ck * 20 + j] = woff[(size_t)j * CI * 9 + ck];
  }
  __syncthreads();

  const int idx = blockIdx.x * TPB + tid;
  const int HW = H * W;
  const int w = idx % W;
  const int h = (idx / W) % H;
  const int b = idx / HW;
  const float* xb = x + (size_t)b * CI * HW;

  float offv[18];
#pragma unroll
  for (int j = 0; j < 18; j++) offv[j] = boff[j];
#pragma unroll
  for (int c = 0; c < CI; c++) {
    const float* xc = xb + (size_t)c * HW;
#pragma unroll
    for (int t = 0; t < 9; t++) {
      int yy = h - 1 + t / 3, xx = w - 1 + t % 3;
      float v = 0.f;
      if (yy >= 0 && yy < H && xx >= 0 && xx < W) v = xc[yy * W + xx];
      const float* wr = &s_wo[(c * 9 + t) * 20];
#pragma unroll
      for (int j = 0; j < 18; j++) offv[j] = fmaf(v, wr[j], offv[j]);
    }
  }

  float acc[CO];
#pragma unroll
  for (int o = 0; o < CO; o++) acc[o] = 0.f;

#pragma unroll
  for (int k = 0; k < 9; k++) {
    float py = (float)(h - 1 + k / 3) + offv[2 * k];
    float px = (float)(w - 1 + k % 3) + offv[2 * k + 1];
    float fy = floorf(py), fx = floorf(px);
    float wy = py - fy, wx = px - fx;
    int y0 = (int)fy, x0 = (int)fx;
    int y1 = y0 + 1, x1 = x0 + 1;
    bool vy0 = (y0 >= 0) & (y0 < H), vy1 = (y1 >= 0) & (y1 < H);
    bool vx0 = (x0 >= 0) & (x0 < W), vx1 = (x1 >= 0) & (x1 < W);
    int yc0 = min(max(y0, 0), H - 1), yc1 = min(max(y1, 0), H - 1);
    int xc0 = min(max(x0, 0), W - 1), xc1 = min(max(x1, 0), W - 1);
    float w00 = (vy0 && vx0) ? (1.f - wy) * (1.f - wx) : 0.f;
    float w01 = (vy0 && vx1) ? (1.f - wy) * wx : 0.f;
    float w10 = (vy1 && vx0) ? wy * (1.f - wx) : 0.f;
    float w11 = (vy1 && vx1) ? wy * wx : 0.f;
    int a00 = yc0 * W + xc0, a01 = yc0 * W + xc1;
    int a10 = yc1 * W + xc0, a11 = yc1 * W + xc1;
#pragma unroll
    for (int c = 0; c < CI; c++) {
      const float* xc = xb + (size_t)c * HW;
      float sv = xc[a00] * w00 + xc[a01] * w01 + xc[a10] * w10 + xc[a11] * w11;
      const float* wr = &s_wm[(c * 9 + k) * CO];
#pragma unroll
      for (int o4 = 0; o4 < CO; o4 += 4) {
        float4 wv = *(const float4*)&wr[o4];
        acc[o4 + 0] = fmaf(sv, wv.x, acc[o4 + 0]);
        acc[o4 + 1] = fmaf(sv, wv.y, acc[o4 + 1]);
        acc[o4 + 2] = fmaf(sv, wv.z, acc[o4 + 2]);
        acc[o4 + 3] = fmaf(sv, wv.w, acc[o4 + 3]);
      }
    }
  }

  float* op = out + (size_t)b * CO * HW + h * W + w;
#pragma unroll
  for (int o = 0; o < CO; o++) op[(size_t)o * HW] = acc[o];
}

// ---------------------------------------------------------------------------
// Offset conv: thread = (pixel, group of 6 offset channels). acc[6].
// Weights for this block's jg-group staged in LDS transposed to
// [c*9+t][u pad 8] and read as broadcast float4+float2 (no global weight
// loads in the hot loop -> no spill).
// ---------------------------------------------------------------------------
template<int CI>
__global__ __launch_bounds__(TPB, 4) void off_conv_lds(
    const float* __restrict__ x, const float* __restrict__ woff,
    const float* __restrict__ boff, float* __restrict__ off,
    int B, int H, int W) {
  __shared__ float s_wj[CI * 9 * 8];  // [c*9+t][u], u padded 6->8

  const int tid = threadIdx.x;
  const int HW = H * W;
  const int blk0 = blockIdx.x * TPB;          // first global idx of block
  const int jg = (blk0 / HW) % 3;             // uniform per block (HW % TPB == 0)
  const int b = blk0 / (3 * HW);

  for (int t = tid; t < CI * 9 * 6; t += TPB) {
    int ck = t / 6, u = t % 6;
    s_wj[ck * 8 + u] = woff[((size_t)(jg * 6 + u) * CI * 9) + ck];
  }
  __syncthreads();

  const int px = (blk0 + tid) % HW;
  const int w = px % W, h = px / W;
  const float* xb = x + (size_t)b * CI * HW;

  float acc[6];
#pragma unroll
  for (int u = 0; u < 6; u++) acc[u] = boff[jg * 6 + u];

#pragma unroll 2
  for (int c = 0; c < CI; c++) {
    const float* xc = xb + (size_t)c * HW;
#pragma unroll
    for (int t = 0; t < 9; t++) {
      int yy = h - 1 + t / 3, xx = w - 1 + t % 3;
      float v = 0.f;
      if (yy >= 0 && yy < H && xx >= 0 && xx < W) v = xc[yy * W + xx];
      const float* wr = &s_wj[(c * 9 + t) * 8];
      float4 w0 = *(const float4*)wr;
      float2 w1 = *(const float2*)(wr + 4);
      acc[0] = fmaf(v, w0.x, acc[0]);
      acc[1] = fmaf(v, w0.y, acc[1]);
      acc[2] = fmaf(v, w0.z, acc[2]);
      acc[3] = fmaf(v, w0.w, acc[3]);
      acc[4] = fmaf(v, w1.x, acc[4]);
      acc[5] = fmaf(v, w1.y, acc[5]);
    }
  }
#pragma unroll
  for (int u = 0; u < 6; u++)
    off[((size_t)b * 18 + jg * 6 + u) * HW + px] = acc[u];
}

// ---------------------------------------------------------------------------
// Deform conv, output-channel split: block = 256 pixels x one og group of
// COG=16 channels. acc[16]; weights from LDS broadcast.
// ---------------------------------------------------------------------------
template<int CI, int CO, int OGC>
__global__ __launch_bounds__(TPB, 4) void dfc_og(
    const float* __restrict__ x, const float* __restrict__ off,
    const float* __restrict__ wmain, float* __restrict__ out,
    int B, int H, int W) {
  constexpr int COG = CO / OGC;
  __shared__ float s_wm[CI * 9 * COG];

  const int og = blockIdx.x % OGC;
  const int pxb = blockIdx.x / OGC;
  const int tid = threadIdx.x;
  for (int t = tid; t < CI * 9 * COG; t += TPB) {
    int ck = t / COG, o = t % COG;
    s_wm[t] = wmain[((size_t)(og * COG + o) * CI * 9) + ck];
  }
  __syncthreads();

  const int idx = pxb * TPB + tid;
  const int HW = H * W;
  const int w = idx % W;
  const int h = (idx / W) % H;
  const int b = idx / HW;
  const float* xb = x + (size_t)b * CI * HW;

  float offv[18];
  const float* ob = off + (size_t)b * 18 * HW + h * W + w;
#pragma unroll
  for (int j = 0; j < 18; j++) offv[j] = ob[(size_t)j * HW];

  float acc[COG];
#pragma unroll
  for (int o = 0; o < COG; o++) acc[o] = 0.f;

#pragma unroll
  for (int k = 0; k < 9; k++) {
    float py = (float)(h - 1 + k / 3) + offv[2 * k];
    float px = (float)(w - 1 + k % 3) + offv[2 * k + 1];
    float fy = floorf(py), fx = floorf(px);
    float wy = py - fy, wx = px - fx;
    int y0 = (int)fy, x0 = (int)fx;
    int y1 = y0 + 1, x1 = x0 + 1;
    bool vy0 = (y0 >= 0) & (y0 < H), vy1 = (y1 >= 0) & (y1 < H);
    bool vx0 = (x0 >= 0) & (x0 < W), vx1 = (x1 >= 0) & (x1 < W);
    int yc0 = min(max(y0, 0), H - 1), yc1 = min(max(y1, 0), H - 1);
    int xc0 = min(max(x0, 0), W - 1), xc1 = min(max(x1, 0), W - 1);
    float w00 = (vy0 && vx0) ? (1.f - wy) * (1.f - wx) : 0.f;
    float w01 = (vy0 && vx1) ? (1.f - wy) * wx : 0.f;
    float w10 = (vy1 && vx0) ? wy * (1.f - wx) : 0.f;
    float w11 = (vy1 && vx1) ? wy * wx : 0.f;
    int a00 = yc0 * W + xc0, a01 = yc0 * W + xc1;
    int a10 = yc1 * W + xc0, a11 = yc1 * W + xc1;
#pragma unroll 2
    for (int c = 0; c < CI; c++) {
      const float* xc = xb + (size_t)c * HW;
      float sv = xc[a00] * w00 + xc[a01] * w01 + xc[a10] * w10 + xc[a11] * w11;
      const float* wr = &s_wm[(c * 9 + k) * COG];
#pragma unroll
      for (int o4 = 0; o4 < COG; o4 += 4) {
        float4 wv = *(const float4*)&wr[o4];
        acc[o4 + 0] = fmaf(sv, wv.x, acc[o4 + 0]);
        acc[o4 + 1] = fmaf(sv, wv.y, acc[o4 + 1]);
        acc[o4 + 2] = fmaf(sv, wv.z, acc[o4 + 2]);
        acc[o4 + 3] = fmaf(sv, wv.w, acc[o4 + 3]);
      }
    }
  }

  float* op = out + ((size_t)b * CO + og * COG) * HW + h * W + w;
#pragma unroll
  for (int o = 0; o < COG; o++) op[(size_t)o * HW] = acc[o];
}

// ---------------------------------------------------------------------------
// BatchNorm (training stats) + LeakyReLU (+ optional 2x2 maxpool)
// ---------------------------------------------------------------------------
__global__ void bn_stats_kernel(const float* __restrict__ y,
                                double* __restrict__ st,
                                int B, int C, int HW, int NB) {
  int c = blockIdx.x / NB;
  int sl = blockIdx.x % NB;
  int tid = threadIdx.x;
  double s = 0.0, s2 = 0.0;
  int HW4 = HW >> 2;
  for (int b = 0; b < B; b++) {
    const float4* p = (const float4*)(y + ((size_t)b * C + c) * HW);
    for (int i = sl * TPB + tid; i < HW4; i += NB * TPB) {
      float4 v = p[i];
      s += (double)v.x + (double)v.y + (double)v.z + (double)v.w;
      s2 += (double)v.x * v.x + (double)v.y * v.y
          + (double)v.z * v.z + (double)v.w * v.w;
    }
  }
  __shared__ double rs[TPB], rq[TPB];
  rs[tid] = s;
  rq[tid] = s2;
  __syncthreads();
  for (int o = TPB / 2; o > 0; o >>= 1) {
    if (tid < o) { rs[tid] += rs[tid + o]; rq[tid] += rq[tid + o]; }
    __syncthreads();
  }
  if (tid == 0) {
    atomicAdd(&st[2 * c], rs[0]);
    atomicAdd(&st[2 * c + 1], rq[0]);
  }
}

__global__ void bn_finalize_kernel(const double* __restrict__ st,
                                   const float* __restrict__ g,
                                   const float* __restrict__ bb,
                                   float* __restrict__ ss, int C, int N) {
  int c = threadIdx.x;
  if (c >= C) return;
  double mean = st[2 * c] / N;
  double var = st[2 * c + 1] / N - mean * mean;
  float inv = (float)(1.0 / sqrt(var + 1e-5));
  float sc = g[c] * inv;
  ss[c] = sc;
  ss[C + c] = bb[c] - (float)mean * sc;
}

__global__ void bn_apply_kernel(const float* __restrict__ y,
                                const float* __restrict__ ss,
                                float* __restrict__ out, int C, int HW, int n) {
  int i = blockIdx.x * TPB + threadIdx.x;
  if (i >= n) return;
  int c = (i / HW) % C;
  float v = fmaf(y[i], ss[c], ss[C + c]);
  out[i] = v > 0.f ? v : 0.01f * v;
}

__global__ void bn_apply_pool_kernel(const float* __restrict__ y,
                                     const float* __restrict__ ss,
                                     float* __restrict__ out,
                                     int C, int H, int W, int n) {
  int i = blockIdx.x * TPB + threadIdx.x;
  if (i >= n) return;
  int Wp = W >> 1, Hp = H >> 1;
  int pw = i % Wp;
  int ph = (i / Wp) % Hp;
  int c = (i / (Wp * Hp)) % C;
  int b = i / (Wp * Hp * C);
  const float* yp = y + (((size_t)b * C + c) * H + 2 * ph) * W + 2 * pw;
  float sc = ss[c], sh = ss[C + c];
  float2 t0 = *(const float2*)yp;
  float2 t1 = *(const float2*)(yp + W);
  float v0 = fmaf(t0.x, sc, sh); v0 = v0 > 0.f ? v0 : 0.01f * v0;
  float v1 = fmaf(t0.y, sc, sh); v1 = v1 > 0.f ? v1 : 0.01f * v1;
  float v2 = fmaf(t1.x, sc, sh); v2 = v2 > 0.f ? v2 : 0.01f * v2;
  float v3 = fmaf(t1.y, sc, sh); v3 = v3 > 0.f ? v3 : 0.01f * v3;
  out[i] = fmaxf(fmaxf(v0, v1), fmaxf(v2, v3));
}

extern "C" void kernel_launch(void* const* d_in, const int* in_sizes, int n_in,
                              void* d_out, int out_size, void* d_ws, size_t ws_size,
                              hipStream_t stream) {
  const float* x = (const float*)d_in[0];
  const float *woff[5], *boff[5], *wm[5], *g[5], *bb[5];
  for (int i = 0; i < 5; i++) {
    woff[i] = (const float*)d_in[1 + 5 * i + 0];
    boff[i] = (const float*)d_in[1 + 5 * i + 1];
    wm[i]   = (const float*)d_in[1 + 5 * i + 2];
    g[i]    = (const float*)d_in[1 + 5 * i + 3];
    bb[i]   = (const float*)d_in[1 + 5 * i + 4];
  }

  const size_t need = (size_t)(16777216 + 4718592 + 4194304 + 2097152) * 4 + 1280 + 640;
  if (ws_size < need) return;

  float* conv_buf = (float*)d_ws;          // up to [8,16,128,1024] = 67 MB
  float* off_buf = conv_buf + 16777216;    // offsets (max L1: 18.9 MB)
  float* xa = off_buf + 4718592;           // x1 / x3
  float* xb2 = xa + 4194304;               // x2 / x4
  double* st = (double*)(xb2 + 2097152);
  float* ss = (float*)(st + 160);

  const int B = 8;

  auto bn = [&](const float* ybuf, int C, int H, int W, int NB,
                const float* gg, const float* bbb, float* outp, bool pool) {
    hipMemsetAsync(st, 0, 2 * C * sizeof(double), stream);
    bn_stats_kernel<<<C * NB, TPB, 0, stream>>>(ybuf, st, B, C, H * W, NB);
    bn_finalize_kernel<<<1, TPB, 0, stream>>>(st, gg, bbb, ss, C, B * H * W);
    if (pool) {
      int n = B * C * (H / 2) * (W / 2);
      bn_apply_pool_kernel<<<(n + TPB - 1) / TPB, TPB, 0, stream>>>(ybuf, ss, outp, C, H, W, n);
    } else {
      int n = B * C * H * W;
      bn_apply_kernel<<<(n + TPB - 1) / TPB, TPB, 0, stream>>>(ybuf, ss, outp, C, H * W, n);
    }
  };

  // ---- Layer 0: CI=1, CO=16, 128x1024, fused offsets, pool -> xa
  {
    const int H = 128, W = 1024;
    dfc_fused<1, 16><<<B * H * W / TPB, TPB, 0, stream>>>(
        x, woff[0], boff[0], wm[0], conv_buf, B, H, W);
    bn(conv_buf, 16, H, W, 32, g[0], bb[0], xa, true);
  }
  // ---- Layer 1: CI=16, CO=32, 64x512, pool -> xb2
  {
    const int H = 64, W = 512;
    off_conv_lds<16><<<B * 3 * H * W / TPB, TPB, 0, stream>>>(
        xa, woff[1], boff[1], off_buf, B, H, W);
    dfc_og<16, 32, 2><<<(B * H * W / TPB) * 2, TPB, 0, stream>>>(
        xa, off_buf, wm[1], conv_buf, B, H, W);
    bn(conv_buf, 32, H, W, 32, g[1], bb[1], xb2, true);
  }
  // ---- Layer 2: CI=32, CO=48, 32x256, pool -> xa
  {
    const int H = 32, W = 256;
    off_conv_lds<32><<<B * 3 * H * W / TPB, TPB, 0, stream>>>(
        xb2, woff[2], boff[2], off_buf, B, H, W);
    dfc_og<32, 48, 3><<<(B * H * W / TPB) * 3, TPB, 0, stream>>>(
        xb2, off_buf, wm[2], conv_buf, B, H, W);
    bn(conv_buf, 48, H, W, 16, g[2], bb[2], xa, true);
  }
  // ---- Layer 3: CI=48, CO=64, 16x128, no pool -> xb2
  {
    const int H = 16, W = 128;
    off_conv_lds<48><<<B * 3 * H * W / TPB, TPB, 0, stream>>>(
        xa, woff[3], boff[3], off_buf, B, H, W);
    dfc_og<48, 64, 4><<<(B * H * W / TPB) * 4, TPB, 0, stream>>>(
        xa, off_buf, wm[3], conv_buf, B, H, W);
    bn(conv_buf, 64, H, W, 8, g[3], bb[3], xb2, false);
  }
  // ---- Layer 4: CI=64, CO=80, 16x128, no pool -> d_out
  {
    const int H = 16, W = 128;
    off_conv_lds<64><<<B * 3 * H * W / TPB, TPB, 0, stream>>>(
        xb2, woff[4], boff[4], off_buf, B, H, W);
    dfc_og<64, 80, 5><<<(B * H * W / TPB) * 5, TPB, 0, stream>>>(
        xb2, off_buf, wm[4], conv_buf, B, H, W);
    bn(conv_buf, 80, H, W, 8, g[4], bb[4], (float*)d_out, false);
  }
}

// Round 6
// 861.422 us; speedup vs baseline: 2.2768x; 1.8006x over previous
//
#include <hip/hip_runtime.h>
#include <math.h>

#define TPB 256

// ---------------------------------------------------------------------------
// Geometry:
//   x: [8, 1, 128, 1024] f32
//   L0: CI=1,  CO=16, 128x1024, pool -> 64x512   (fused offsets)
//   L1: CI=16, CO=32, 64x512,   pool -> 32x256
//   L2: CI=32, CO=48, 32x256,   pool -> 16x128
//   L3: CI=48, CO=64, 16x128,   no pool
//   L4: CI=64, CO=80, 16x128,   no pool -> d_out
//
// Anti-spill discipline (R2-R4 lesson: 64-VGPR allocations + hoisted load
// floods -> 0.5-3 GB scratch traffic, <8% VALUBusy):
//   * __launch_bounds__(TPB) only — no min-wave cap on the allocator
//   * #pragma unroll 1 on channel loops — bounded in-flight load window
//   * ALL weights read via wave-uniform addresses from packed layouts ->
//     compiler emits scalar s_loads (SGPRs, 0 VGPR cost, constant cache)
// R5 bug fixed here: offset-weight pack segments used s.p[seg-1] (= woff of
// the PREVIOUS layer, layer0 for seg6) — must be s.p[seg].
// ---------------------------------------------------------------------------

// Packed-weight workspace offsets (floats)
#define OWM0 0
#define OWM1 144
#define OWM2 4752
#define OWM3 18576
#define OWM4 46224
#define OWO0 92304
#define OWO1 92484
#define OWO2 95940
#define OWO3 102852
#define OWO4 113220
#define PACK_FLOATS 131072

struct PackSrc { const float* p[10]; };  // 0-4: wmain, 5-9: woff

// wmainP[l]: dst[(k*CI+c)*CO + o] = wm[(o*CI+c)*9 + k]
// woffP0   : dst[t*20 + j]        = wo0[j*9 + t]            (j<18, pad 20)
// woffP[l] : dst[((jg*CI*9)+(c*9+t))*8 + u] = wo[((jg*6+u)*CI+c)*9+t] (u<6, pad 8)
__global__ void pack_weights(PackSrc s, float* __restrict__ dst) {
  int seg = blockIdx.y;
  int idx = blockIdx.x * TPB + threadIdx.x;
  int CI, CO, ow;
  if (seg < 5) {
    if (seg == 0)      { CI = 1;  CO = 16; ow = OWM0; }
    else if (seg == 1) { CI = 16; CO = 32; ow = OWM1; }
    else if (seg == 2) { CI = 32; CO = 48; ow = OWM2; }
    else if (seg == 3) { CI = 48; CO = 64; ow = OWM3; }
    else               { CI = 64; CO = 80; ow = OWM4; }
    int n = 9 * CI * CO;
    if (idx >= n) return;
    int o = idx % CO, rest = idx / CO;
    int c = rest % CI, k = rest / CI;
    dst[ow + idx] = s.p[seg][((size_t)o * CI + c) * 9 + k];
  } else if (seg == 5) {
    if (idx >= 180) return;
    int j = idx % 20, t = idx / 20;
    dst[OWO0 + idx] = (j < 18) ? s.p[5][j * 9 + t] : 0.f;
  } else {
    if (seg == 6)      { CI = 16; ow = OWO1; }
    else if (seg == 7) { CI = 32; ow = OWO2; }
    else if (seg == 8) { CI = 48; ow = OWO3; }
    else               { CI = 64; ow = OWO4; }
    int n = 3 * CI * 9 * 8;
    if (idx >= n) return;
    int u = idx % 8, r = idx / 8;
    int t = r % 9, c = (r / 9) % CI, jg = r / (9 * CI);
    dst[ow + idx] = (u < 6) ? s.p[seg][((size_t)(jg * 6 + u) * CI + c) * 9 + t] : 0.f;
  }
}

// ---------------------------------------------------------------------------
// L0: CI=1 -> load the 3x3 patch once, compute 18 offsets + 16 outputs.
// ---------------------------------------------------------------------------
__global__ __launch_bounds__(TPB) void dfc_fused0(
    const float* __restrict__ x, const float* __restrict__ woP,   // [9][20]
    const float* __restrict__ boff, const float* __restrict__ wmP, // [9][16]
    float* __restrict__ out, int B, int H, int W) {
  const int idx = blockIdx.x * TPB + threadIdx.x;
  const int HW = H * W;
  const int w = idx % W;
  const int h = (idx / W) % H;
  const int b = idx / HW;
  const float* xp = x + (size_t)b * HW;

  float xv[9];
#pragma unroll
  for (int t = 0; t < 9; t++) {
    int yy = h - 1 + t / 3, xx = w - 1 + t % 3;
    xv[t] = (yy >= 0 && yy < H && xx >= 0 && xx < W) ? xp[yy * W + xx] : 0.f;
  }

  float offv[18];
#pragma unroll
  for (int j = 0; j < 18; j++) offv[j] = boff[j];
#pragma unroll
  for (int t = 0; t < 9; t++) {
    const float* wr = &woP[t * 20];
#pragma unroll
    for (int j = 0; j < 18; j++) offv[j] = fmaf(xv[t], wr[j], offv[j]);
  }

  float acc[16];
#pragma unroll
  for (int o = 0; o < 16; o++) acc[o] = 0.f;

#pragma unroll
  for (int k = 0; k < 9; k++) {
    float py = (float)(h - 1 + k / 3) + offv[2 * k];
    float px = (float)(w - 1 + k % 3) + offv[2 * k + 1];
    float fy = floorf(py), fx = floorf(px);
    float wy = py - fy, wx = px - fx;
    int y0 = (int)fy, x0 = (int)fx;
    int y1 = y0 + 1, x1 = x0 + 1;
    bool vy0 = (y0 >= 0) & (y0 < H), vy1 = (y1 >= 0) & (y1 < H);
    bool vx0 = (x0 >= 0) & (x0 < W), vx1 = (x1 >= 0) & (x1 < W);
    int yc0 = min(max(y0, 0), H - 1), yc1 = min(max(y1, 0), H - 1);
    int xc0 = min(max(x0, 0), W - 1), xc1 = min(max(x1, 0), W - 1);
    float w00 = (vy0 && vx0) ? (1.f - wy) * (1.f - wx) : 0.f;
    float w01 = (vy0 && vx1) ? (1.f - wy) * wx : 0.f;
    float w10 = (vy1 && vx0) ? wy * (1.f - wx) : 0.f;
    float w11 = (vy1 && vx1) ? wy * wx : 0.f;
    float sv = xp[yc0 * W + xc0] * w00 + xp[yc0 * W + xc1] * w01
             + xp[yc1 * W + xc0] * w10 + xp[yc1 * W + xc1] * w11;
    const float* wr = &wmP[k * 16];
#pragma unroll
    for (int o = 0; o < 16; o++) acc[o] = fmaf(sv, wr[o], acc[o]);
  }

  float* op = out + (size_t)b * 16 * HW + h * W + w;
#pragma unroll
  for (int o = 0; o < 16; o++) op[(size_t)o * HW] = acc[o];
}

// ---------------------------------------------------------------------------
// Offset conv (L1-L4): block = (b, jg, pixel-block) from blockIdx only, so
// all weight addresses are wave-uniform -> s_load. acc[6] per thread.
// ---------------------------------------------------------------------------
template<int CI>
__global__ __launch_bounds__(TPB) void off_conv(
    const float* __restrict__ x, const float* __restrict__ wP,  // [3][CI*9][8]
    const float* __restrict__ boff, float* __restrict__ off,
    int B, int H, int W) {
  const int HW = H * W;
  const int npb = HW / TPB;
  const int pxb = blockIdx.x % npb;
  const int jg = (blockIdx.x / npb) % 3;
  const int b = blockIdx.x / (3 * npb);
  const int px = pxb * TPB + threadIdx.x;
  const int w = px % W, h = px / W;
  const float* xb = x + (size_t)b * CI * HW;
  const float* wj = wP + (size_t)jg * CI * 9 * 8;

  float acc[6];
#pragma unroll
  for (int u = 0; u < 6; u++) acc[u] = boff[jg * 6 + u];

#pragma unroll 1
  for (int c = 0; c < CI; c++) {
    const float* xc = xb + (size_t)c * HW;
    const float* wc = wj + c * 72;
#pragma unroll
    for (int t = 0; t < 9; t++) {
      int yy = h - 1 + t / 3, xx = w - 1 + t % 3;
      float v = (yy >= 0 && yy < H && xx >= 0 && xx < W) ? xc[yy * W + xx] : 0.f;
      const float* wr = wc + t * 8;
      acc[0] = fmaf(v, wr[0], acc[0]);
      acc[1] = fmaf(v, wr[1], acc[1]);
      acc[2] = fmaf(v, wr[2], acc[2]);
      acc[3] = fmaf(v, wr[3], acc[3]);
      acc[4] = fmaf(v, wr[4], acc[4]);
      acc[5] = fmaf(v, wr[5], acc[5]);
    }
  }
#pragma unroll
  for (int u = 0; u < 6; u++)
    off[((size_t)b * 18 + jg * 6 + u) * HW + px] = acc[u];
}

// ---------------------------------------------------------------------------
// Deform conv (L1-L4), output-channel split: og from blockIdx -> uniform
// weight addresses (s_load). acc[16], channel loop unroll 1.
// ---------------------------------------------------------------------------
template<int CI, int CO, int OGC>
__global__ __launch_bounds__(TPB) void dfc_og(
    const float* __restrict__ x, const float* __restrict__ off,
    const float* __restrict__ wP,   // [9*CI][CO]
    float* __restrict__ out, int B, int H, int W) {
  constexpr int COG = CO / OGC;   // 16
  const int HW = H * W;
  const int npb = HW / TPB;
  const int og = blockIdx.x % OGC;
  const int pxb = (blockIdx.x / OGC) % npb;
  const int b = blockIdx.x / (OGC * npb);
  const int px = pxb * TPB + threadIdx.x;
  const int w = px % W, h = px / W;
  const float* xb = x + (size_t)b * CI * HW;

  float offv[18];
  const float* ob = off + (size_t)b * 18 * HW + px;
#pragma unroll
  for (int j = 0; j < 18; j++) offv[j] = ob[(size_t)j * HW];

  float acc[COG];
#pragma unroll
  for (int o = 0; o < COG; o++) acc[o] = 0.f;

#pragma unroll
  for (int k = 0; k < 9; k++) {
    float py = (float)(h - 1 + k / 3) + offv[2 * k];
    float pxx = (float)(w - 1 + k % 3) + offv[2 * k + 1];
    float fy = floorf(py), fx = floorf(pxx);
    float wy = py - fy, wx = pxx - fx;
    int y0 = (int)fy, x0 = (int)fx;
    int y1 = y0 + 1, x1 = x0 + 1;
    bool vy0 = (y0 >= 0) & (y0 < H), vy1 = (y1 >= 0) & (y1 < H);
    bool vx0 = (x0 >= 0) & (x0 < W), vx1 = (x1 >= 0) & (x1 < W);
    int yc0 = min(max(y0, 0), H - 1), yc1 = min(max(y1, 0), H - 1);
    int xc0 = min(max(x0, 0), W - 1), xc1 = min(max(x1, 0), W - 1);
    float w00 = (vy0 && vx0) ? (1.f - wy) * (1.f - wx) : 0.f;
    float w01 = (vy0 && vx1) ? (1.f - wy) * wx : 0.f;
    float w10 = (vy1 && vx0) ? wy * (1.f - wx) : 0.f;
    float w11 = (vy1 && vx1) ? wy * wx : 0.f;
    int a00 = yc0 * W + xc0, a01 = yc0 * W + xc1;
    int a10 = yc1 * W + xc0, a11 = yc1 * W + xc1;
#pragma unroll 1
    for (int c = 0; c < CI; c++) {
      const float* xc = xb + (size_t)c * HW;
      float sv = xc[a00] * w00 + xc[a01] * w01 + xc[a10] * w10 + xc[a11] * w11;
      const float* wr = wP + (size_t)(k * CI + c) * CO + og * COG;
#pragma unroll
      for (int o = 0; o < COG; o++) acc[o] = fmaf(sv, wr[o], acc[o]);
    }
  }

  float* op = out + ((size_t)b * CO + og * COG) * HW + px;
#pragma unroll
  for (int o = 0; o < COG; o++) op[(size_t)o * HW] = acc[o];
}

// ---------------------------------------------------------------------------
// BatchNorm (training stats) + LeakyReLU (+ optional 2x2 maxpool)
// ---------------------------------------------------------------------------
__global__ void bn_stats_kernel(const float* __restrict__ y,
                                double* __restrict__ st,
                                int B, int C, int HW, int NB) {
  int c = blockIdx.x / NB;
  int sl = blockIdx.x % NB;
  int tid = threadIdx.x;
  double s = 0.0, s2 = 0.0;
  int HW4 = HW >> 2;
  for (int b = 0; b < B; b++) {
    const float4* p = (const float4*)(y + ((size_t)b * C + c) * HW);
    for (int i = sl * TPB + tid; i < HW4; i += NB * TPB) {
      float4 v = p[i];
      s += (double)v.x + (double)v.y + (double)v.z + (double)v.w;
      s2 += (double)v.x * v.x + (double)v.y * v.y
          + (double)v.z * v.z + (double)v.w * v.w;
    }
  }
  __shared__ double rs[TPB], rq[TPB];
  rs[tid] = s;
  rq[tid] = s2;
  __syncthreads();
  for (int o = TPB / 2; o > 0; o >>= 1) {
    if (tid < o) { rs[tid] += rs[tid + o]; rq[tid] += rq[tid + o]; }
    __syncthreads();
  }
  if (tid == 0) {
    atomicAdd(&st[2 * c], rs[0]);
    atomicAdd(&st[2 * c + 1], rq[0]);
  }
}

__global__ void bn_finalize_kernel(const double* __restrict__ st,
                                   const float* __restrict__ g,
                                   const float* __restrict__ bb,
                                   float* __restrict__ ss, int C, int N) {
  int c = threadIdx.x;
  if (c >= C) return;
  double mean = st[2 * c] / N;
  double var = st[2 * c + 1] / N - mean * mean;
  float inv = (float)(1.0 / sqrt(var + 1e-5));
  float sc = g[c] * inv;
  ss[c] = sc;
  ss[C + c] = bb[c] - (float)mean * sc;
}

__global__ void bn_apply_kernel(const float* __restrict__ y,
                                const float* __restrict__ ss,
                                float* __restrict__ out, int C, int HW, int n) {
  int i = blockIdx.x * TPB + threadIdx.x;
  if (i >= n) return;
  int c = (i / HW) % C;
  float v = fmaf(y[i], ss[c], ss[C + c]);
  out[i] = v > 0.f ? v : 0.01f * v;
}

__global__ void bn_apply_pool_kernel(const float* __restrict__ y,
                                     const float* __restrict__ ss,
                                     float* __restrict__ out,
                                     int C, int H, int W, int n) {
  int i = blockIdx.x * TPB + threadIdx.x;
  if (i >= n) return;
  int Wp = W >> 1, Hp = H >> 1;
  int pw = i % Wp;
  int ph = (i / Wp) % Hp;
  int c = (i / (Wp * Hp)) % C;
  int b = i / (Wp * Hp * C);
  const float* yp = y + (((size_t)b * C + c) * H + 2 * ph) * W + 2 * pw;
  float sc = ss[c], sh = ss[C + c];
  float2 t0 = *(const float2*)yp;
  float2 t1 = *(const float2*)(yp + W);
  float v0 = fmaf(t0.x, sc, sh); v0 = v0 > 0.f ? v0 : 0.01f * v0;
  float v1 = fmaf(t0.y, sc, sh); v1 = v1 > 0.f ? v1 : 0.01f * v1;
  float v2 = fmaf(t1.x, sc, sh); v2 = v2 > 0.f ? v2 : 0.01f * v2;
  float v3 = fmaf(t1.y, sc, sh); v3 = v3 > 0.f ? v3 : 0.01f * v3;
  out[i] = fmaxf(fmaxf(v0, v1), fmaxf(v2, v3));
}

extern "C" void kernel_launch(void* const* d_in, const int* in_sizes, int n_in,
                              void* d_out, int out_size, void* d_ws, size_t ws_size,
                              hipStream_t stream) {
  const float* x = (const float*)d_in[0];
  const float *woff[5], *boff[5], *wm[5], *g[5], *bb[5];
  for (int i = 0; i < 5; i++) {
    woff[i] = (const float*)d_in[1 + 5 * i + 0];
    boff[i] = (const float*)d_in[1 + 5 * i + 1];
    wm[i]   = (const float*)d_in[1 + 5 * i + 2];
    g[i]    = (const float*)d_in[1 + 5 * i + 3];
    bb[i]   = (const float*)d_in[1 + 5 * i + 4];
  }

  const size_t need =
      (size_t)(16777216 + 4718592 + 4194304 + 2097152 + PACK_FLOATS) * 4 + 1280 + 640;
  if (ws_size < need) return;

  float* conv_buf = (float*)d_ws;          // up to [8,16,128,1024] = 67 MB
  float* off_buf = conv_buf + 16777216;    // offsets (max L1: 18.9 MB)
  float* xa = off_buf + 4718592;           // x1 / x3
  float* xb2 = xa + 4194304;               // x2 / x4
  float* wpk = xb2 + 2097152;              // packed weights (512 KB)
  double* st = (double*)(wpk + PACK_FLOATS);
  float* ss = (float*)(st + 160);

  const int B = 8;

  // Pack all weights into s_load-friendly layouts
  {
    PackSrc psrc;
    for (int i = 0; i < 5; i++) { psrc.p[i] = wm[i]; psrc.p[5 + i] = woff[i]; }
    pack_weights<<<dim3(180, 10), TPB, 0, stream>>>(psrc, wpk);
  }

  auto bn = [&](const float* ybuf, int C, int H, int W, int NB,
                const float* gg, const float* bbb, float* outp, bool pool) {
    hipMemsetAsync(st, 0, 2 * C * sizeof(double), stream);
    bn_stats_kernel<<<C * NB, TPB, 0, stream>>>(ybuf, st, B, C, H * W, NB);
    bn_finalize_kernel<<<1, TPB, 0, stream>>>(st, gg, bbb, ss, C, B * H * W);
    if (pool) {
      int n = B * C * (H / 2) * (W / 2);
      bn_apply_pool_kernel<<<(n + TPB - 1) / TPB, TPB, 0, stream>>>(ybuf, ss, outp, C, H, W, n);
    } else {
      int n = B * C * H * W;
      bn_apply_kernel<<<(n + TPB - 1) / TPB, TPB, 0, stream>>>(ybuf, ss, outp, C, H * W, n);
    }
  };

  // ---- Layer 0: CI=1, CO=16, 128x1024, fused offsets, pool -> xa
  {
    const int H = 128, W = 1024;
    dfc_fused0<<<B * H * W / TPB, TPB, 0, stream>>>(
        x, wpk + OWO0, boff[0], wpk + OWM0, conv_buf, B, H, W);
    bn(conv_buf, 16, H, W, 32, g[0], bb[0], xa, true);
  }
  // ---- Layer 1: CI=16, CO=32, 64x512, pool -> xb2
  {
    const int H = 64, W = 512;
    off_conv<16><<<B * 3 * (H * W / TPB), TPB, 0, stream>>>(
        xa, wpk + OWO1, boff[1], off_buf, B, H, W);
    dfc_og<16, 32, 2><<<B * (H * W / TPB) * 2, TPB, 0, stream>>>(
        xa, off_buf, wpk + OWM1, conv_buf, B, H, W);
    bn(conv_buf, 32, H, W, 32, g[1], bb[1], xb2, true);
  }
  // ---- Layer 2: CI=32, CO=48, 32x256, pool -> xa
  {
    const int H = 32, W = 256;
    off_conv<32><<<B * 3 * (H * W / TPB), TPB, 0, stream>>>(
        xb2, wpk + OWO2, boff[2], off_buf, B, H, W);
    dfc_og<32, 48, 3><<<B * (H * W / TPB) * 3, TPB, 0, stream>>>(
        xb2, off_buf, wpk + OWM2, conv_buf, B, H, W);
    bn(conv_buf, 48, H, W, 16, g[2], bb[2], xa, true);
  }
  // ---- Layer 3: CI=48, CO=64, 16x128, no pool -> xb2
  {
    const int H = 16, W = 128;
    off_conv<48><<<B * 3 * (H * W / TPB), TPB, 0, stream>>>(
        xa, wpk + OWO3, boff[3], off_buf, B, H, W);
    dfc_og<48, 64, 4><<<B * (H * W / TPB) * 4, TPB, 0, stream>>>(
        xa, off_buf, wpk + OWM3, conv_buf, B, H, W);
    bn(conv_buf, 64, H, W, 8, g[3], bb[3], xb2, false);
  }
  // ---- Layer 4: CI=64, CO=80, 16x128, no pool -> d_out
  {
    const int H = 16, W = 128;
    off_conv<64><<<B * 3 * (H * W / TPB), TPB, 0, stream>>>(
        xb2, wpk + OWO4, boff[4], off_buf, B, H, W);
    dfc_og<64, 80, 5><<<B * (H * W / TPB) * 5, TPB, 0, stream>>>(
        xb2, off_buf, wpk + OWM4, conv_buf, B, H, W);
    bn(conv_buf, 80, H, W, 8, g[4], bb[4], (float*)d_out, false);
  }
}

// Round 7
// 804.450 us; speedup vs baseline: 2.4380x; 1.0708x over previous
//
#include <hip/hip_runtime.h>
#include <math.h>

#define TPB 256

// ---------------------------------------------------------------------------
// Geometry:
//   x: [8, 1, 128, 1024] f32
//   L0: CI=1,  CO=16, 128x1024, pool -> 64x512   (fused offsets)
//   L1: CI=16, CO=32, 64x512,   pool -> 32x256
//   L2: CI=32, CO=48, 32x256,   pool -> 16x128
//   L3: CI=48, CO=64, 16x128,   no pool
//   L4: CI=64, CO=80, 16x128,   no pool -> d_out
//
// R6 lessons kept: no min-wave launch_bounds cap; weights via wave-uniform
// s_load layouts; bounded unroll. R7 adds: c-unroll x4 (ILP for gather
// latency) + XCD-aware block swizzle (each XCD works one batch -> L2-resident
// inputs; R6 showed 222 MB FETCH vs 51 MB ideal from cross-XCD thrash).
// ---------------------------------------------------------------------------

// Packed-weight workspace offsets (floats)
#define OWM0 0
#define OWM1 144
#define OWM2 4752
#define OWM3 18576
#define OWM4 46224
#define OWO0 92304
#define OWO1 92484
#define OWO2 95940
#define OWO3 102852
#define OWO4 113220
#define PACK_FLOATS 131072

struct PackSrc { const float* p[10]; };  // 0-4: wmain, 5-9: woff

__global__ void pack_weights(PackSrc s, float* __restrict__ dst) {
  int seg = blockIdx.y;
  int idx = blockIdx.x * TPB + threadIdx.x;
  int CI, CO, ow;
  if (seg < 5) {
    if (seg == 0)      { CI = 1;  CO = 16; ow = OWM0; }
    else if (seg == 1) { CI = 16; CO = 32; ow = OWM1; }
    else if (seg == 2) { CI = 32; CO = 48; ow = OWM2; }
    else if (seg == 3) { CI = 48; CO = 64; ow = OWM3; }
    else               { CI = 64; CO = 80; ow = OWM4; }
    int n = 9 * CI * CO;
    if (idx >= n) return;
    int o = idx % CO, rest = idx / CO;
    int c = rest % CI, k = rest / CI;
    dst[ow + idx] = s.p[seg][((size_t)o * CI + c) * 9 + k];
  } else if (seg == 5) {
    if (idx >= 180) return;
    int j = idx % 20, t = idx / 20;
    dst[OWO0 + idx] = (j < 18) ? s.p[5][j * 9 + t] : 0.f;
  } else {
    if (seg == 6)      { CI = 16; ow = OWO1; }
    else if (seg == 7) { CI = 32; ow = OWO2; }
    else if (seg == 8) { CI = 48; ow = OWO3; }
    else               { CI = 64; ow = OWO4; }
    int n = 3 * CI * 9 * 8;
    if (idx >= n) return;
    int u = idx % 8, r = idx / 8;
    int t = r % 9, c = (r / 9) % CI, jg = r / (9 * CI);
    dst[ow + idx] = (u < 6) ? s.p[seg][((size_t)(jg * 6 + u) * CI + c) * 9 + t] : 0.f;
  }
}

// XCD-aware swizzle: nwg % 8 == 0 (checked at launch sites). XCD x gets the
// contiguous work chunk [x*nwg/8, (x+1)*nwg/8) — one batch per XCD here.
__device__ __forceinline__ int xcd_swz(int bid, int nwg) {
  return (bid & 7) * (nwg >> 3) + (bid >> 3);
}

// ---------------------------------------------------------------------------
// L0: CI=1 -> load the 3x3 patch once, compute 18 offsets + 16 outputs.
// ---------------------------------------------------------------------------
__global__ __launch_bounds__(TPB) void dfc_fused0(
    const float* __restrict__ x, const float* __restrict__ woP,   // [9][20]
    const float* __restrict__ boff, const float* __restrict__ wmP, // [9][16]
    float* __restrict__ out, int B, int H, int W) {
  const int nwg = gridDim.x;
  const int idx = xcd_swz(blockIdx.x, nwg) * TPB + threadIdx.x;
  const int HW = H * W;
  const int w = idx % W;
  const int h = (idx / W) % H;
  const int b = idx / HW;
  const float* xp = x + (size_t)b * HW;

  float xv[9];
#pragma unroll
  for (int t = 0; t < 9; t++) {
    int yy = h - 1 + t / 3, xx = w - 1 + t % 3;
    xv[t] = (yy >= 0 && yy < H && xx >= 0 && xx < W) ? xp[yy * W + xx] : 0.f;
  }

  float offv[18];
#pragma unroll
  for (int j = 0; j < 18; j++) offv[j] = boff[j];
#pragma unroll
  for (int t = 0; t < 9; t++) {
    const float* wr = &woP[t * 20];
#pragma unroll
    for (int j = 0; j < 18; j++) offv[j] = fmaf(xv[t], wr[j], offv[j]);
  }

  float acc[16];
#pragma unroll
  for (int o = 0; o < 16; o++) acc[o] = 0.f;

#pragma unroll
  for (int k = 0; k < 9; k++) {
    float py = (float)(h - 1 + k / 3) + offv[2 * k];
    float px = (float)(w - 1 + k % 3) + offv[2 * k + 1];
    float fy = floorf(py), fx = floorf(px);
    float wy = py - fy, wx = px - fx;
    int y0 = (int)fy, x0 = (int)fx;
    int y1 = y0 + 1, x1 = x0 + 1;
    bool vy0 = (y0 >= 0) & (y0 < H), vy1 = (y1 >= 0) & (y1 < H);
    bool vx0 = (x0 >= 0) & (x0 < W), vx1 = (x1 >= 0) & (x1 < W);
    int yc0 = min(max(y0, 0), H - 1), yc1 = min(max(y1, 0), H - 1);
    int xc0 = min(max(x0, 0), W - 1), xc1 = min(max(x1, 0), W - 1);
    float w00 = (vy0 && vx0) ? (1.f - wy) * (1.f - wx) : 0.f;
    float w01 = (vy0 && vx1) ? (1.f - wy) * wx : 0.f;
    float w10 = (vy1 && vx0) ? wy * (1.f - wx) : 0.f;
    float w11 = (vy1 && vx1) ? wy * wx : 0.f;
    float sv = xp[yc0 * W + xc0] * w00 + xp[yc0 * W + xc1] * w01
             + xp[yc1 * W + xc0] * w10 + xp[yc1 * W + xc1] * w11;
    const float* wr = &wmP[k * 16];
#pragma unroll
    for (int o = 0; o < 16; o++) acc[o] = fmaf(sv, wr[o], acc[o]);
  }

  float* op = out + (size_t)b * 16 * HW + h * W + w;
#pragma unroll
  for (int o = 0; o < 16; o++) op[(size_t)o * HW] = acc[o];
}

// ---------------------------------------------------------------------------
// Offset conv (L1-L4): block = (b, jg, pixel-block); weights via s_load.
// acc[6]; c-unroll x2 for gather ILP.
// ---------------------------------------------------------------------------
template<int CI>
__global__ __launch_bounds__(TPB) void off_conv(
    const float* __restrict__ x, const float* __restrict__ wP,  // [3][CI*9][8]
    const float* __restrict__ boff, float* __restrict__ off,
    int B, int H, int W) {
  const int HW = H * W;
  const int npb = HW / TPB;
  const int bid = xcd_swz(blockIdx.x, gridDim.x);
  const int pxb = bid % npb;
  const int jg = (bid / npb) % 3;
  const int b = bid / (3 * npb);
  const int px = pxb * TPB + threadIdx.x;
  const int w = px % W, h = px / W;
  const float* xb = x + (size_t)b * CI * HW;
  const float* wj = wP + (size_t)jg * CI * 9 * 8;

  float acc[6];
#pragma unroll
  for (int u = 0; u < 6; u++) acc[u] = boff[jg * 6 + u];

#pragma unroll 1
  for (int c = 0; c < CI; c += 2) {
    const float* xc0 = xb + (size_t)c * HW;
    const float* xc1 = xc0 + HW;
    const float* wc0 = wj + c * 72;
    const float* wc1 = wc0 + 72;
#pragma unroll
    for (int t = 0; t < 9; t++) {
      int yy = h - 1 + t / 3, xx = w - 1 + t % 3;
      bool vld = (yy >= 0 && yy < H && xx >= 0 && xx < W);
      int a = yy * W + xx;
      float v0 = vld ? xc0[a] : 0.f;
      float v1 = vld ? xc1[a] : 0.f;
      const float* wr0 = wc0 + t * 8;
      const float* wr1 = wc1 + t * 8;
#pragma unroll
      for (int u = 0; u < 6; u++) {
        acc[u] = fmaf(v0, wr0[u], acc[u]);
        acc[u] = fmaf(v1, wr1[u], acc[u]);
      }
    }
  }
#pragma unroll
  for (int u = 0; u < 6; u++)
    off[((size_t)b * 18 + jg * 6 + u) * HW + px] = acc[u];
}

// ---------------------------------------------------------------------------
// Deform conv (L1-L4), output-channel split. acc[16]; weights via s_load;
// c-unroll x4 (16 gathers in flight per step).
// ---------------------------------------------------------------------------
template<int CI, int CO, int OGC>
__global__ __launch_bounds__(TPB) void dfc_og(
    const float* __restrict__ x, const float* __restrict__ off,
    const float* __restrict__ wP,   // [9*CI][CO]
    float* __restrict__ out, int B, int H, int W) {
  constexpr int COG = CO / OGC;   // 16
  const int HW = H * W;
  const int npb = HW / TPB;
  const int bid = xcd_swz(blockIdx.x, gridDim.x);
  const int og = bid % OGC;
  const int pxb = (bid / OGC) % npb;
  const int b = bid / (OGC * npb);
  const int px = pxb * TPB + threadIdx.x;
  const int w = px % W, h = px / W;
  const float* xb = x + (size_t)b * CI * HW;

  float offv[18];
  const float* ob = off + (size_t)b * 18 * HW + px;
#pragma unroll
  for (int j = 0; j < 18; j++) offv[j] = ob[(size_t)j * HW];

  float acc[COG];
#pragma unroll
  for (int o = 0; o < COG; o++) acc[o] = 0.f;

#pragma unroll
  for (int k = 0; k < 9; k++) {
    float py = (float)(h - 1 + k / 3) + offv[2 * k];
    float pxx = (float)(w - 1 + k % 3) + offv[2 * k + 1];
    float fy = floorf(py), fx = floorf(pxx);
    float wy = py - fy, wx = pxx - fx;
    int y0 = (int)fy, x0 = (int)fx;
    int y1 = y0 + 1, x1 = x0 + 1;
    bool vy0 = (y0 >= 0) & (y0 < H), vy1 = (y1 >= 0) & (y1 < H);
    bool vx0 = (x0 >= 0) & (x0 < W), vx1 = (x1 >= 0) & (x1 < W);
    int yc0 = min(max(y0, 0), H - 1), yc1 = min(max(y1, 0), H - 1);
    int xc0 = min(max(x0, 0), W - 1), xc1 = min(max(x1, 0), W - 1);
    float w00 = (vy0 && vx0) ? (1.f - wy) * (1.f - wx) : 0.f;
    float w01 = (vy0 && vx1) ? (1.f - wy) * wx : 0.f;
    float w10 = (vy1 && vx0) ? wy * (1.f - wx) : 0.f;
    float w11 = (vy1 && vx1) ? wy * wx : 0.f;
    int a00 = yc0 * W + xc0, a01 = yc0 * W + xc1;
    int a10 = yc1 * W + xc0, a11 = yc1 * W + xc1;
#pragma unroll 1
    for (int c = 0; c < CI; c += 4) {
      const float* xc0p = xb + (size_t)c * HW;
      const float* xc1p = xc0p + HW;
      const float* xc2p = xc1p + HW;
      const float* xc3p = xc2p + HW;
      float sv0 = xc0p[a00] * w00 + xc0p[a01] * w01 + xc0p[a10] * w10 + xc0p[a11] * w11;
      float sv1 = xc1p[a00] * w00 + xc1p[a01] * w01 + xc1p[a10] * w10 + xc1p[a11] * w11;
      float sv2 = xc2p[a00] * w00 + xc2p[a01] * w01 + xc2p[a10] * w10 + xc2p[a11] * w11;
      float sv3 = xc3p[a00] * w00 + xc3p[a01] * w01 + xc3p[a10] * w10 + xc3p[a11] * w11;
      const float* wr = wP + (size_t)(k * CI + c) * CO + og * COG;
#pragma unroll
      for (int o = 0; o < COG; o++) {
        float a0 = fmaf(sv0, wr[o], acc[o]);
        float a1 = fmaf(sv1, wr[o + CO], a0);
        float a2 = fmaf(sv2, wr[o + 2 * CO], a1);
        acc[o] = fmaf(sv3, wr[o + 3 * CO], a2);
      }
    }
  }

  float* op = out + ((size_t)b * CO + og * COG) * HW + px;
#pragma unroll
  for (int o = 0; o < COG; o++) op[(size_t)o * HW] = acc[o];
}

// ---------------------------------------------------------------------------
// BatchNorm (training stats) + LeakyReLU (+ optional 2x2 maxpool)
// ---------------------------------------------------------------------------
__global__ void bn_stats_kernel(const float* __restrict__ y,
                                double* __restrict__ st,
                                int B, int C, int HW, int NB) {
  int c = blockIdx.x / NB;
  int sl = blockIdx.x % NB;
  int tid = threadIdx.x;
  double s = 0.0, s2 = 0.0;
  int HW4 = HW >> 2;
  for (int b = 0; b < B; b++) {
    const float4* p = (const float4*)(y + ((size_t)b * C + c) * HW);
    for (int i = sl * TPB + tid; i < HW4; i += NB * TPB) {
      float4 v = p[i];
      s += (double)v.x + (double)v.y + (double)v.z + (double)v.w;
      s2 += (double)v.x * v.x + (double)v.y * v.y
          + (double)v.z * v.z + (double)v.w * v.w;
    }
  }
  __shared__ double rs[TPB], rq[TPB];
  rs[tid] = s;
  rq[tid] = s2;
  __syncthreads();
  for (int o = TPB / 2; o > 0; o >>= 1) {
    if (tid < o) { rs[tid] += rs[tid + o]; rq[tid] += rq[tid + o]; }
    __syncthreads();
  }
  if (tid == 0) {
    atomicAdd(&st[2 * c], rs[0]);
    atomicAdd(&st[2 * c + 1], rq[0]);
  }
}

__global__ void bn_finalize_kernel(const double* __restrict__ st,
                                   const float* __restrict__ g,
                                   const float* __restrict__ bb,
                                   float* __restrict__ ss, int C, int N) {
  int c = threadIdx.x;
  if (c >= C) return;
  double mean = st[2 * c] / N;
  double var = st[2 * c + 1] / N - mean * mean;
  float inv = (float)(1.0 / sqrt(var + 1e-5));
  float sc = g[c] * inv;
  ss[c] = sc;
  ss[C + c] = bb[c] - (float)mean * sc;
}

__global__ void bn_apply_kernel(const float* __restrict__ y,
                                const float* __restrict__ ss,
                                float* __restrict__ out, int C, int HW, int n) {
  int i = blockIdx.x * TPB + threadIdx.x;
  if (i >= n) return;
  int c = (i / HW) % C;
  float v = fmaf(y[i], ss[c], ss[C + c]);
  out[i] = v > 0.f ? v : 0.01f * v;
}

__global__ void bn_apply_pool_kernel(const float* __restrict__ y,
                                     const float* __restrict__ ss,
                                     float* __restrict__ out,
                                     int C, int H, int W, int n) {
  int i = blockIdx.x * TPB + threadIdx.x;
  if (i >= n) return;
  int Wp = W >> 1, Hp = H >> 1;
  int pw = i % Wp;
  int ph = (i / Wp) % Hp;
  int c = (i / (Wp * Hp)) % C;
  int b = i / (Wp * Hp * C);
  const float* yp = y + (((size_t)b * C + c) * H + 2 * ph) * W + 2 * pw;
  float sc = ss[c], sh = ss[C + c];
  float2 t0 = *(const float2*)yp;
  float2 t1 = *(const float2*)(yp + W);
  float v0 = fmaf(t0.x, sc, sh); v0 = v0 > 0.f ? v0 : 0.01f * v0;
  float v1 = fmaf(t0.y, sc, sh); v1 = v1 > 0.f ? v1 : 0.01f * v1;
  float v2 = fmaf(t1.x, sc, sh); v2 = v2 > 0.f ? v2 : 0.01f * v2;
  float v3 = fmaf(t1.y, sc, sh); v3 = v3 > 0.f ? v3 : 0.01f * v3;
  out[i] = fmaxf(fmaxf(v0, v1), fmaxf(v2, v3));
}

extern "C" void kernel_launch(void* const* d_in, const int* in_sizes, int n_in,
                              void* d_out, int out_size, void* d_ws, size_t ws_size,
                              hipStream_t stream) {
  const float* x = (const float*)d_in[0];
  const float *woff[5], *boff[5], *wm[5], *g[5], *bb[5];
  for (int i = 0; i < 5; i++) {
    woff[i] = (const float*)d_in[1 + 5 * i + 0];
    boff[i] = (const float*)d_in[1 + 5 * i + 1];
    wm[i]   = (const float*)d_in[1 + 5 * i + 2];
    g[i]    = (const float*)d_in[1 + 5 * i + 3];
    bb[i]   = (const float*)d_in[1 + 5 * i + 4];
  }

  const size_t need =
      (size_t)(16777216 + 4718592 + 4194304 + 2097152 + PACK_FLOATS) * 4 + 1280 + 640;
  if (ws_size < need) return;

  float* conv_buf = (float*)d_ws;          // up to [8,16,128,1024] = 67 MB
  float* off_buf = conv_buf + 16777216;    // offsets (max L1: 18.9 MB)
  float* xa = off_buf + 4718592;           // x1 / x3
  float* xb2 = xa + 4194304;               // x2 / x4
  float* wpk = xb2 + 2097152;              // packed weights (512 KB)
  double* st = (double*)(wpk + PACK_FLOATS);
  float* ss = (float*)(st + 160);

  const int B = 8;

  // Pack all weights into s_load-friendly layouts
  {
    PackSrc psrc;
    for (int i = 0; i < 5; i++) { psrc.p[i] = wm[i]; psrc.p[5 + i] = woff[i]; }
    pack_weights<<<dim3(180, 10), TPB, 0, stream>>>(psrc, wpk);
  }

  auto bn = [&](const float* ybuf, int C, int H, int W, int NB,
                const float* gg, const float* bbb, float* outp, bool pool) {
    hipMemsetAsync(st, 0, 2 * C * sizeof(double), stream);
    bn_stats_kernel<<<C * NB, TPB, 0, stream>>>(ybuf, st, B, C, H * W, NB);
    bn_finalize_kernel<<<1, TPB, 0, stream>>>(st, gg, bbb, ss, C, B * H * W);
    if (pool) {
      int n = B * C * (H / 2) * (W / 2);
      bn_apply_pool_kernel<<<(n + TPB - 1) / TPB, TPB, 0, stream>>>(ybuf, ss, outp, C, H, W, n);
    } else {
      int n = B * C * H * W;
      bn_apply_kernel<<<(n + TPB - 1) / TPB, TPB, 0, stream>>>(ybuf, ss, outp, C, H * W, n);
    }
  };

  // ---- Layer 0: CI=1, CO=16, 128x1024, fused offsets, pool -> xa
  {
    const int H = 128, W = 1024;
    dfc_fused0<<<B * H * W / TPB, TPB, 0, stream>>>(
        x, wpk + OWO0, boff[0], wpk + OWM0, conv_buf, B, H, W);
    bn(conv_buf, 16, H, W, 32, g[0], bb[0], xa, true);
  }
  // ---- Layer 1: CI=16, CO=32, 64x512, pool -> xb2
  {
    const int H = 64, W = 512;
    off_conv<16><<<B * 3 * (H * W / TPB), TPB, 0, stream>>>(
        xa, wpk + OWO1, boff[1], off_buf, B, H, W);
    dfc_og<16, 32, 2><<<B * (H * W / TPB) * 2, TPB, 0, stream>>>(
        xa, off_buf, wpk + OWM1, conv_buf, B, H, W);
    bn(conv_buf, 32, H, W, 32, g[1], bb[1], xb2, true);
  }
  // ---- Layer 2: CI=32, CO=48, 32x256, pool -> xa
  {
    const int H = 32, W = 256;
    off_conv<32><<<B * 3 * (H * W / TPB), TPB, 0, stream>>>(
        xb2, wpk + OWO2, boff[2], off_buf, B, H, W);
    dfc_og<32, 48, 3><<<B * (H * W / TPB) * 3, TPB, 0, stream>>>(
        xb2, off_buf, wpk + OWM2, conv_buf, B, H, W);
    bn(conv_buf, 48, H, W, 16, g[2], bb[2], xa, true);
  }
  // ---- Layer 3: CI=48, CO=64, 16x128, no pool -> xb2
  {
    const int H = 16, W = 128;
    off_conv<48><<<B * 3 * (H * W / TPB), TPB, 0, stream>>>(
        xa, wpk + OWO3, boff[3], off_buf, B, H, W);
    dfc_og<48, 64, 4><<<B * (H * W / TPB) * 4, TPB, 0, stream>>>(
        xa, off_buf, wpk + OWM3, conv_buf, B, H, W);
    bn(conv_buf, 64, H, W, 8, g[3], bb[3], xb2, false);
  }
  // ---- Layer 4: CI=64, CO=80, 16x128, no pool -> d_out
  {
    const int H = 16, W = 128;
    off_conv<64><<<B * 3 * (H * W / TPB), TPB, 0, stream>>>(
        xb2, wpk + OWO4, boff[4], off_buf, B, H, W);
    dfc_og<64, 80, 5><<<B * (H * W / TPB) * 5, TPB, 0, stream>>>(
        xb2, off_buf, wpk + OWM4, conv_buf, B, H, W);
    bn(conv_buf, 80, H, W, 8, g[4], bb[4], (float*)d_out, false);
  }
}

// Round 8
// 561.705 us; speedup vs baseline: 3.4916x; 1.4322x over previous
//
#include <hip/hip_runtime.h>
#include <math.h>

#define TPB 256

// ---------------------------------------------------------------------------
// Geometry:
//   x: [8, 1, 128, 1024] f32
//   L0: CI=1,  CO=16, 128x1024, pool -> 64x512   (fused offsets)
//   L1: CI=16, CO=32, 64x512,   pool -> 32x256
//   L2: CI=32, CO=48, 32x256,   pool -> 16x128
//   L3: CI=48, CO=64, 16x128,   no pool
//   L4: CI=64, CO=80, 16x128,   no pool -> d_out
//
// R8: inter-layer activations x1..x4 are NHWC (channels innermost) so every
// bilinear-corner / conv-tap read is a float4 (4 channels per VMEM instr,
// 4x fewer gather instructions — R7 showed gather-issue, not traffic, was
// the limiter: FETCH 17.6MB, VALUBusy 23%, HBM 4%). dfc outputs stay NCHW
// for coalesced BN stats/apply; BN-apply(+pool) writes NHWC for next layer.
// Kept from R6/R7: no launch_bounds min-wave cap, wave-uniform s_load
// weights, bounded unrolls, XCD-aware swizzle (one batch per XCD).
// ---------------------------------------------------------------------------

// Packed-weight workspace offsets (floats)
#define OWM0 0
#define OWM1 144
#define OWM2 4752
#define OWM3 18576
#define OWM4 46224
#define OWO0 92304
#define OWO1 92484
#define OWO2 95940
#define OWO3 102852
#define OWO4 113220
#define PACK_FLOATS 131072

struct PackSrc { const float* p[10]; };  // 0-4: wmain, 5-9: woff

__global__ void pack_weights(PackSrc s, float* __restrict__ dst) {
  int seg = blockIdx.y;
  int idx = blockIdx.x * TPB + threadIdx.x;
  int CI, CO, ow;
  if (seg < 5) {
    if (seg == 0)      { CI = 1;  CO = 16; ow = OWM0; }
    else if (seg == 1) { CI = 16; CO = 32; ow = OWM1; }
    else if (seg == 2) { CI = 32; CO = 48; ow = OWM2; }
    else if (seg == 3) { CI = 48; CO = 64; ow = OWM3; }
    else               { CI = 64; CO = 80; ow = OWM4; }
    int n = 9 * CI * CO;
    if (idx >= n) return;
    int o = idx % CO, rest = idx / CO;
    int c = rest % CI, k = rest / CI;
    dst[ow + idx] = s.p[seg][((size_t)o * CI + c) * 9 + k];
  } else if (seg == 5) {
    if (idx >= 180) return;
    int j = idx % 20, t = idx / 20;
    dst[OWO0 + idx] = (j < 18) ? s.p[5][j * 9 + t] : 0.f;
  } else {
    if (seg == 6)      { CI = 16; ow = OWO1; }
    else if (seg == 7) { CI = 32; ow = OWO2; }
    else if (seg == 8) { CI = 48; ow = OWO3; }
    else               { CI = 64; ow = OWO4; }
    int n = 3 * CI * 9 * 8;
    if (idx >= n) return;
    int u = idx % 8, r = idx / 8;
    int t = r % 9, c = (r / 9) % CI, jg = r / (9 * CI);
    dst[ow + idx] = (u < 6) ? s.p[seg][((size_t)(jg * 6 + u) * CI + c) * 9 + t] : 0.f;
  }
}

// XCD-aware swizzle: nwg % 8 == 0 at every launch site.
__device__ __forceinline__ int xcd_swz(int bid, int nwg) {
  return (bid & 7) * (nwg >> 3) + (bid >> 3);
}

// ---------------------------------------------------------------------------
// L0: CI=1 (NCHW==NHWC) -> fused offsets + deform conv, out NCHW.
// ---------------------------------------------------------------------------
__global__ __launch_bounds__(TPB) void dfc_fused0(
    const float* __restrict__ x, const float* __restrict__ woP,   // [9][20]
    const float* __restrict__ boff, const float* __restrict__ wmP, // [9][16]
    float* __restrict__ out, int B, int H, int W) {
  const int idx = xcd_swz(blockIdx.x, gridDim.x) * TPB + threadIdx.x;
  const int HW = H * W;
  const int w = idx % W;
  const int h = (idx / W) % H;
  const int b = idx / HW;
  const float* xp = x + (size_t)b * HW;

  float xv[9];
#pragma unroll
  for (int t = 0; t < 9; t++) {
    int yy = h - 1 + t / 3, xx = w - 1 + t % 3;
    xv[t] = (yy >= 0 && yy < H && xx >= 0 && xx < W) ? xp[yy * W + xx] : 0.f;
  }

  float offv[18];
#pragma unroll
  for (int j = 0; j < 18; j++) offv[j] = boff[j];
#pragma unroll
  for (int t = 0; t < 9; t++) {
    const float* wr = &woP[t * 20];
#pragma unroll
    for (int j = 0; j < 18; j++) offv[j] = fmaf(xv[t], wr[j], offv[j]);
  }

  float acc[16];
#pragma unroll
  for (int o = 0; o < 16; o++) acc[o] = 0.f;

#pragma unroll
  for (int k = 0; k < 9; k++) {
    float py = (float)(h - 1 + k / 3) + offv[2 * k];
    float px = (float)(w - 1 + k % 3) + offv[2 * k + 1];
    float fy = floorf(py), fx = floorf(px);
    float wy = py - fy, wx = px - fx;
    int y0 = (int)fy, x0 = (int)fx;
    int y1 = y0 + 1, x1 = x0 + 1;
    bool vy0 = (y0 >= 0) & (y0 < H), vy1 = (y1 >= 0) & (y1 < H);
    bool vx0 = (x0 >= 0) & (x0 < W), vx1 = (x1 >= 0) & (x1 < W);
    int yc0 = min(max(y0, 0), H - 1), yc1 = min(max(y1, 0), H - 1);
    int xc0 = min(max(x0, 0), W - 1), xc1 = min(max(x1, 0), W - 1);
    float w00 = (vy0 && vx0) ? (1.f - wy) * (1.f - wx) : 0.f;
    float w01 = (vy0 && vx1) ? (1.f - wy) * wx : 0.f;
    float w10 = (vy1 && vx0) ? wy * (1.f - wx) : 0.f;
    float w11 = (vy1 && vx1) ? wy * wx : 0.f;
    float sv = xp[yc0 * W + xc0] * w00 + xp[yc0 * W + xc1] * w01
             + xp[yc1 * W + xc0] * w10 + xp[yc1 * W + xc1] * w11;
    const float* wr = &wmP[k * 16];
#pragma unroll
    for (int o = 0; o < 16; o++) acc[o] = fmaf(sv, wr[o], acc[o]);
  }

  float* op = out + (size_t)b * 16 * HW + h * W + w;
#pragma unroll
  for (int o = 0; o < 16; o++) op[(size_t)o * HW] = acc[o];
}

// ---------------------------------------------------------------------------
// Offset conv (L1-L4): x is NHWC -> per tap, CI/4 float4 loads. acc[6].
// Weights wave-uniform s_load from [jg][c*9+t][8] layout.
// ---------------------------------------------------------------------------
template<int CI, int TPBK>
__global__ __launch_bounds__(TPBK) void off_conv(
    const float* __restrict__ x, const float* __restrict__ wP,
    const float* __restrict__ boff, float* __restrict__ off,
    int B, int H, int W) {
  const int HW = H * W;
  const int npb = HW / TPBK;
  const int bid = xcd_swz(blockIdx.x, gridDim.x);
  const int pxb = bid % npb;
  const int jg = (bid / npb) % 3;
  const int b = bid / (3 * npb);
  const int px = pxb * TPBK + threadIdx.x;
  const int w = px % W, h = px / W;
  const float* xb = x + (size_t)b * HW * CI;
  const float* wj = wP + (size_t)jg * CI * 9 * 8;

  float acc[6];
#pragma unroll
  for (int u = 0; u < 6; u++) acc[u] = boff[jg * 6 + u];

#pragma unroll 1
  for (int t = 0; t < 9; t++) {
    int yy = h - 1 + t / 3, xx = w - 1 + t % 3;
    bool vld = (yy >= 0 && yy < H && xx >= 0 && xx < W);
    int a = vld ? (yy * W + xx) : 0;
    const float* xp = xb + (size_t)a * CI;
    const float* wt = wj + t * 8;
#pragma unroll 4
    for (int cg = 0; cg < CI / 4; cg++) {
      float4 v = *(const float4*)(xp + cg * 4);
      float s0 = vld ? v.x : 0.f;
      float s1 = vld ? v.y : 0.f;
      float s2 = vld ? v.z : 0.f;
      float s3 = vld ? v.w : 0.f;
      const float* w0 = wt + (size_t)cg * 4 * 72;
#pragma unroll
      for (int u = 0; u < 6; u++) {
        float a0 = fmaf(s0, w0[u], acc[u]);
        float a1 = fmaf(s1, w0[72 + u], a0);
        float a2 = fmaf(s2, w0[144 + u], a1);
        acc[u] = fmaf(s3, w0[216 + u], a2);
      }
    }
  }
#pragma unroll
  for (int u = 0; u < 6; u++)
    off[((size_t)b * 18 + jg * 6 + u) * HW + px] = acc[u];
}

// ---------------------------------------------------------------------------
// Deform conv (L1-L4), og-split, x NHWC: per k-tap x c-group = 4 float4
// corner loads (16 channels-worth of samples per 4 VMEM instrs).
// Out NCHW. acc[16]. Weights wave-uniform s_load from [k*CI+c][CO].
// ---------------------------------------------------------------------------
template<int CI, int CO, int OGC, int TPBK>
__global__ __launch_bounds__(TPBK) void dfc_og(
    const float* __restrict__ x, const float* __restrict__ off,
    const float* __restrict__ wP, float* __restrict__ out,
    int B, int H, int W) {
  constexpr int COG = CO / OGC;   // 16
  const int HW = H * W;
  const int npb = HW / TPBK;
  const int bid = xcd_swz(blockIdx.x, gridDim.x);
  const int og = bid % OGC;
  const int pxb = (bid / OGC) % npb;
  const int b = bid / (OGC * npb);
  const int px = pxb * TPBK + threadIdx.x;
  const int w = px % W, h = px / W;
  const float* xb = x + (size_t)b * HW * CI;   // NHWC

  float offv[18];
  const float* ob = off + (size_t)b * 18 * HW + px;
#pragma unroll
  for (int j = 0; j < 18; j++) offv[j] = ob[(size_t)j * HW];

  float acc[COG];
#pragma unroll
  for (int o = 0; o < COG; o++) acc[o] = 0.f;

#pragma unroll
  for (int k = 0; k < 9; k++) {
    float py = (float)(h - 1 + k / 3) + offv[2 * k];
    float pxx = (float)(w - 1 + k % 3) + offv[2 * k + 1];
    float fy = floorf(py), fx = floorf(pxx);
    float wy = py - fy, wx = pxx - fx;
    int y0 = (int)fy, x0 = (int)fx;
    int y1 = y0 + 1, x1 = x0 + 1;
    bool vy0 = (y0 >= 0) & (y0 < H), vy1 = (y1 >= 0) & (y1 < H);
    bool vx0 = (x0 >= 0) & (x0 < W), vx1 = (x1 >= 0) & (x1 < W);
    int yc0 = min(max(y0, 0), H - 1), yc1 = min(max(y1, 0), H - 1);
    int xc0 = min(max(x0, 0), W - 1), xc1 = min(max(x1, 0), W - 1);
    float w00 = (vy0 && vx0) ? (1.f - wy) * (1.f - wx) : 0.f;
    float w01 = (vy0 && vx1) ? (1.f - wy) * wx : 0.f;
    float w10 = (vy1 && vx0) ? wy * (1.f - wx) : 0.f;
    float w11 = (vy1 && vx1) ? wy * wx : 0.f;
    const float* p00 = xb + (size_t)(yc0 * W + xc0) * CI;
    const float* p01 = xb + (size_t)(yc0 * W + xc1) * CI;
    const float* p10 = xb + (size_t)(yc1 * W + xc0) * CI;
    const float* p11 = xb + (size_t)(yc1 * W + xc1) * CI;
#pragma unroll 2
    for (int cg = 0; cg < CI / 4; cg++) {
      float4 v00 = *(const float4*)(p00 + cg * 4);
      float4 v01 = *(const float4*)(p01 + cg * 4);
      float4 v10 = *(const float4*)(p10 + cg * 4);
      float4 v11 = *(const float4*)(p11 + cg * 4);
      float s0 = v00.x * w00 + v01.x * w01 + v10.x * w10 + v11.x * w11;
      float s1 = v00.y * w00 + v01.y * w01 + v10.y * w10 + v11.y * w11;
      float s2 = v00.z * w00 + v01.z * w01 + v10.z * w10 + v11.z * w11;
      float s3 = v00.w * w00 + v01.w * w01 + v10.w * w10 + v11.w * w11;
      const float* wr = wP + (size_t)(k * CI + cg * 4) * CO + og * COG;
#pragma unroll
      for (int o = 0; o < COG; o++) {
        float a0 = fmaf(s0, wr[o], acc[o]);
        float a1 = fmaf(s1, wr[CO + o], a0);
        float a2 = fmaf(s2, wr[2 * CO + o], a1);
        acc[o] = fmaf(s3, wr[3 * CO + o], a2);
      }
    }
  }

  float* op = out + ((size_t)b * CO + og * COG) * HW + px;
#pragma unroll
  for (int o = 0; o < COG; o++) op[(size_t)o * HW] = acc[o];
}

// ---------------------------------------------------------------------------
// BatchNorm (training stats, y in NCHW) + LeakyReLU; apply variants write
// NHWC (next-layer input) or NCHW (final output).
// ---------------------------------------------------------------------------
__global__ void bn_stats_kernel(const float* __restrict__ y,
                                double* __restrict__ st,
                                int B, int C, int HW, int NB) {
  int c = blockIdx.x / NB;
  int sl = blockIdx.x % NB;
  int tid = threadIdx.x;
  double s = 0.0, s2 = 0.0;
  int HW4 = HW >> 2;
  for (int b = 0; b < B; b++) {
    const float4* p = (const float4*)(y + ((size_t)b * C + c) * HW);
    for (int i = sl * TPB + tid; i < HW4; i += NB * TPB) {
      float4 v = p[i];
      s += (double)v.x + (double)v.y + (double)v.z + (double)v.w;
      s2 += (double)v.x * v.x + (double)v.y * v.y
          + (double)v.z * v.z + (double)v.w * v.w;
    }
  }
  __shared__ double rs[TPB], rq[TPB];
  rs[tid] = s;
  rq[tid] = s2;
  __syncthreads();
  for (int o = TPB / 2; o > 0; o >>= 1) {
    if (tid < o) { rs[tid] += rs[tid + o]; rq[tid] += rq[tid + o]; }
    __syncthreads();
  }
  if (tid == 0) {
    atomicAdd(&st[2 * c], rs[0]);
    atomicAdd(&st[2 * c + 1], rq[0]);
  }
}

__global__ void bn_finalize_kernel(const double* __restrict__ st,
                                   const float* __restrict__ g,
                                   const float* __restrict__ bb,
                                   float* __restrict__ ss, int C, int N) {
  int c = threadIdx.x;
  if (c >= C) return;
  double mean = st[2 * c] / N;
  double var = st[2 * c + 1] / N - mean * mean;
  float inv = (float)(1.0 / sqrt(var + 1e-5));
  float sc = g[c] * inv;
  ss[c] = sc;
  ss[C + c] = bb[c] - (float)mean * sc;
}

// NCHW -> NCHW (final output)
__global__ void bn_apply_kernel(const float* __restrict__ y,
                                const float* __restrict__ ss,
                                float* __restrict__ out, int C, int HW, int n) {
  int i = blockIdx.x * TPB + threadIdx.x;
  if (i >= n) return;
  int c = (i / HW) % C;
  float v = fmaf(y[i], ss[c], ss[C + c]);
  out[i] = v > 0.f ? v : 0.01f * v;
}

// NCHW -> NHWC (no pool; L3)
__global__ void bn_apply_nhwc_kernel(const float* __restrict__ y,
                                     const float* __restrict__ ss,
                                     float* __restrict__ out,
                                     int C, int H, int W, int n) {
  int i = blockIdx.x * TPB + threadIdx.x;
  if (i >= n) return;
  int c = i % C;
  int pix = i / C;
  int w = pix % W;
  int h = (pix / W) % H;
  int b = pix / (W * H);
  float v = fmaf(y[(((size_t)b * C + c) * H + h) * W + w], ss[c], ss[C + c]);
  out[i] = v > 0.f ? v : 0.01f * v;
}

// NCHW -> 2x2 maxpool -> NHWC (L0,L1,L2)
__global__ void bn_apply_pool_nhwc_kernel(const float* __restrict__ y,
                                          const float* __restrict__ ss,
                                          float* __restrict__ out,
                                          int C, int H, int W, int n) {
  int i = blockIdx.x * TPB + threadIdx.x;
  if (i >= n) return;
  int Wp = W >> 1, Hp = H >> 1;
  int c = i % C;
  int pw = (i / C) % Wp;
  int ph = (i / C / Wp) % Hp;
  int b = i / (C * Wp * Hp);
  const float* yp = y + (((size_t)b * C + c) * H + 2 * ph) * W + 2 * pw;
  float sc = ss[c], sh = ss[C + c];
  float v0 = fmaf(yp[0], sc, sh);     v0 = v0 > 0.f ? v0 : 0.01f * v0;
  float v1 = fmaf(yp[1], sc, sh);     v1 = v1 > 0.f ? v1 : 0.01f * v1;
  float v2 = fmaf(yp[W], sc, sh);     v2 = v2 > 0.f ? v2 : 0.01f * v2;
  float v3 = fmaf(yp[W + 1], sc, sh); v3 = v3 > 0.f ? v3 : 0.01f * v3;
  out[i] = fmaxf(fmaxf(v0, v1), fmaxf(v2, v3));
}

extern "C" void kernel_launch(void* const* d_in, const int* in_sizes, int n_in,
                              void* d_out, int out_size, void* d_ws, size_t ws_size,
                              hipStream_t stream) {
  const float* x = (const float*)d_in[0];
  const float *woff[5], *boff[5], *wm[5], *g[5], *bb[5];
  for (int i = 0; i < 5; i++) {
    woff[i] = (const float*)d_in[1 + 5 * i + 0];
    boff[i] = (const float*)d_in[1 + 5 * i + 1];
    wm[i]   = (const float*)d_in[1 + 5 * i + 2];
    g[i]    = (const float*)d_in[1 + 5 * i + 3];
    bb[i]   = (const float*)d_in[1 + 5 * i + 4];
  }

  const size_t need =
      (size_t)(16777216 + 4718592 + 4194304 + 2097152 + PACK_FLOATS) * 4 + 1280 + 640;
  if (ws_size < need) return;

  float* conv_buf = (float*)d_ws;          // NCHW conv outputs (up to 67 MB)
  float* off_buf = conv_buf + 16777216;    // offsets [b][18][HW]
  float* xa = off_buf + 4718592;           // x1 / x3 (NHWC)
  float* xb2 = xa + 4194304;               // x2 / x4 (NHWC)
  float* wpk = xb2 + 2097152;              // packed weights
  double* st = (double*)(wpk + PACK_FLOATS);
  float* ss = (float*)(st + 160);

  const int B = 8;

  {
    PackSrc psrc;
    for (int i = 0; i < 5; i++) { psrc.p[i] = wm[i]; psrc.p[5 + i] = woff[i]; }
    pack_weights<<<dim3(180, 10), TPB, 0, stream>>>(psrc, wpk);
  }

  auto bn_head = [&](const float* ybuf, int C, int H, int W, int NB,
                     const float* gg, const float* bbb) {
    hipMemsetAsync(st, 0, 2 * C * sizeof(double), stream);
    bn_stats_kernel<<<C * NB, TPB, 0, stream>>>(ybuf, st, B, C, H * W, NB);
    bn_finalize_kernel<<<1, TPB, 0, stream>>>(st, gg, bbb, ss, C, B * H * W);
  };

  // ---- Layer 0: CI=1, CO=16, 128x1024, fused offsets, pool -> xa (NHWC)
  {
    const int H = 128, W = 1024;
    dfc_fused0<<<B * H * W / TPB, TPB, 0, stream>>>(
        x, wpk + OWO0, boff[0], wpk + OWM0, conv_buf, B, H, W);
    bn_head(conv_buf, 16, H, W, 32, g[0], bb[0]);
    int n = B * 16 * (H / 2) * (W / 2);
    bn_apply_pool_nhwc_kernel<<<n / TPB, TPB, 0, stream>>>(
        conv_buf, ss, xa, 16, H, W, n);
  }
  // ---- Layer 1: CI=16, CO=32, 64x512, pool -> xb2 (NHWC)
  {
    const int H = 64, W = 512;
    off_conv<16, 256><<<B * 3 * (H * W / 256), 256, 0, stream>>>(
        xa, wpk + OWO1, boff[1], off_buf, B, H, W);
    dfc_og<16, 32, 2, 256><<<B * (H * W / 256) * 2, 256, 0, stream>>>(
        xa, off_buf, wpk + OWM1, conv_buf, B, H, W);
    bn_head(conv_buf, 32, H, W, 32, g[1], bb[1]);
    int n = B * 32 * (H / 2) * (W / 2);
    bn_apply_pool_nhwc_kernel<<<n / TPB, TPB, 0, stream>>>(
        conv_buf, ss, xb2, 32, H, W, n);
  }
  // ---- Layer 2: CI=32, CO=48, 32x256, pool -> xa (NHWC)
  {
    const int H = 32, W = 256;
    off_conv<32, 256><<<B * 3 * (H * W / 256), 256, 0, stream>>>(
        xb2, wpk + OWO2, boff[2], off_buf, B, H, W);
    dfc_og<32, 48, 3, 256><<<B * (H * W / 256) * 3, 256, 0, stream>>>(
        xb2, off_buf, wpk + OWM2, conv_buf, B, H, W);
    bn_head(conv_buf, 48, H, W, 16, g[2], bb[2]);
    int n = B * 48 * (H / 2) * (W / 2);
    bn_apply_pool_nhwc_kernel<<<n / TPB, TPB, 0, stream>>>(
        conv_buf, ss, xa, 48, H, W, n);
  }
  // ---- Layer 3: CI=48, CO=64, 16x128, no pool -> xb2 (NHWC)
  {
    const int H = 16, W = 128;
    off_conv<48, 64><<<B * 3 * (H * W / 64), 64, 0, stream>>>(
        xa, wpk + OWO3, boff[3], off_buf, B, H, W);
    dfc_og<48, 64, 4, 64><<<B * (H * W / 64) * 4, 64, 0, stream>>>(
        xa, off_buf, wpk + OWM3, conv_buf, B, H, W);
    bn_head(conv_buf, 64, H, W, 8, g[3], bb[3]);
    int n = B * 64 * H * W;
    bn_apply_nhwc_kernel<<<n / TPB, TPB, 0, stream>>>(
        conv_buf, ss, xb2, 64, H, W, n);
  }
  // ---- Layer 4: CI=64, CO=80, 16x128, no pool -> d_out (NCHW)
  {
    const int H = 16, W = 128;
    off_conv<64, 64><<<B * 3 * (H * W / 64), 64, 0, stream>>>(
        xb2, wpk + OWO4, boff[4], off_buf, B, H, W);
    dfc_og<64, 80, 5, 64><<<B * (H * W / 64) * 5, 64, 0, stream>>>(
        xb2, off_buf, wpk + OWM4, conv_buf, B, H, W);
    bn_head(conv_buf, 80, H, W, 8, g[4], bb[4]);
    int n = B * 80 * H * W;
    bn_apply_kernel<<<n / TPB, TPB, 0, stream>>>(
        conv_buf, ss, (float*)d_out, 80, H * W, n);
  }
}